// Round 6
// baseline (349.648 us; speedup 1.0000x reference)
//
#include <hip/hip_runtime.h>
#include <math.h>

#define N_NODES 100000
#define N_EDGES 600000
#define DIN     64
#define DH      128
#define NG      512
#define EPS_BN  1e-5f
#define SCAN_TPB 256
#define N_SCAN_BLK ((N_NODES + SCAN_TPB - 1) / SCAN_TPB)   // 391

typedef unsigned short u16;
typedef unsigned long long u64;
typedef short s16x8 __attribute__((ext_vector_type(8)));
typedef short s16x4 __attribute__((ext_vector_type(4)));
typedef float f32x4 __attribute__((ext_vector_type(4)));

__device__ __forceinline__ u16 f2bf(float x) {
    unsigned u = __builtin_bit_cast(unsigned, x);
    u += 0x7fffu + ((u >> 16) & 1u);   // round-to-nearest-even
    return (u16)(u >> 16);
}
__device__ __forceinline__ float bf2f(u16 h) {
    unsigned u = ((unsigned)h) << 16;
    return __builtin_bit_cast(float, u);
}

// ---------------- degree histogram ----------------
__global__ __launch_bounds__(256) void deg_kernel(const int* __restrict__ dst,
                                                  float* __restrict__ deg, int E) {
    int e = blockIdx.x * blockDim.x + threadIdx.x;
    if (e < E) atomicAdd(&deg[dst[e]], 1.0f);
}

__global__ __launch_bounds__(256) void dis_kernel(const float* __restrict__ deg,
                                                  float* __restrict__ dis,
                                                  int* __restrict__ deg_i, int n) {
    int i = blockIdx.x * blockDim.x + threadIdx.x;
    if (i < n) {
        float d = deg[i];
        dis[i] = rsqrtf(d + 1.0f);   // +1 self loop
        deg_i[i] = (int)d;
    }
}

// ---------------- multi-block scan ----------------
__global__ __launch_bounds__(SCAN_TPB) void scan1_kernel(const int* __restrict__ deg_i,
                                                         int* __restrict__ row_ptr,
                                                         int* __restrict__ blk, int n) {
    __shared__ int sm[SCAN_TPB];
    const int t = threadIdx.x;
    const int i = blockIdx.x * SCAN_TPB + t;
    const int v = (i < n) ? deg_i[i] : 0;
    sm[t] = v;
    __syncthreads();
#pragma unroll
    for (int off = 1; off < SCAN_TPB; off <<= 1) {
        int u = (t >= off) ? sm[t - off] : 0;
        __syncthreads();
        sm[t] += u;
        __syncthreads();
    }
    if (i < n) row_ptr[i] = sm[t] - v;
    if (t == SCAN_TPB - 1) blk[blockIdx.x] = sm[t];
}

__global__ __launch_bounds__(512) void scan2_kernel(int* __restrict__ blk,
                                                    int* __restrict__ row_ptr,
                                                    int nblk, int n) {
    __shared__ int sm[512];
    const int t = threadIdx.x;
    const int v = (t < nblk) ? blk[t] : 0;
    sm[t] = v;
    __syncthreads();
#pragma unroll
    for (int off = 1; off < 512; off <<= 1) {
        int u = (t >= off) ? sm[t - off] : 0;
        __syncthreads();
        sm[t] += u;
        __syncthreads();
    }
    if (t < nblk) blk[t] = sm[t] - v;
    if (t == nblk - 1) row_ptr[n] = sm[t];
}

__global__ __launch_bounds__(SCAN_TPB) void scan3_kernel(int* __restrict__ row_ptr,
                                                         const int* __restrict__ blk, int n) {
    const int i = blockIdx.x * SCAN_TPB + threadIdx.x;
    if (i < n) row_ptr[i] += blk[blockIdx.x];
}

// ---------------- scatter edges into CSR: packed (col | val) 8B single store ----------------
__global__ __launch_bounds__(256) void build_csr_kernel(const int* __restrict__ src,
                                                        const int* __restrict__ dst,
                                                        const float* __restrict__ dis,
                                                        const int* __restrict__ row_ptr,
                                                        int* __restrict__ cursor,
                                                        u64* __restrict__ colval, int E) {
    int e = blockIdx.x * blockDim.x + threadIdx.x;
    if (e >= E) return;
    const int s = src[e];
    const int d = dst[e];
    const int p = atomicAdd(&cursor[d], 1);
    const unsigned fb = __builtin_bit_cast(unsigned, dis[s] * dis[d]);
    colval[row_ptr[d] + p] = ((u64)fb << 32) | (unsigned)s;
}

// ---------------- fp32 -> bf16 convert (x) ----------------
__global__ __launch_bounds__(256) void xcvt_kernel(const float* __restrict__ x,
                                                   u16* __restrict__ xb, long n) {
    long i = ((long)blockIdx.x * blockDim.x + threadIdx.x) * 8;
    if (i >= n) return;
    const float4 a = *(const float4*)(x + i);
    const float4 b = *(const float4*)(x + i + 4);
    s16x8 o;
    o[0] = (short)f2bf(a.x); o[1] = (short)f2bf(a.y);
    o[2] = (short)f2bf(a.z); o[3] = (short)f2bf(a.w);
    o[4] = (short)f2bf(b.x); o[5] = (short)f2bf(b.y);
    o[6] = (short)f2bf(b.z); o[7] = (short)f2bf(b.w);
    *(s16x8*)(xb + i) = o;
}

// ---------------- W[K][N] fp32 -> Wt[N][K] bf16 ----------------
__global__ __launch_bounds__(256) void wt_kernel(const float* __restrict__ W,
                                                 u16* __restrict__ Wt, int K, int N) {
    int idx = blockIdx.x * blockDim.x + threadIdx.x;
    if (idx >= K * N) return;
    int k = idx / N, n = idx % N;
    Wt[(long)n * K + k] = f2bf(W[idx]);
}

// ---------------- fold BN into scale/shift (3 layers) ----------------
__global__ __launch_bounds__(256) void bn_prep_kernel(
    const float* b1, const float* g1, const float* bb1, const float* m1, const float* v1,
    const float* b2, const float* g2, const float* bb2, const float* m2, const float* v2,
    const float* b3, const float* g3, const float* bb3, const float* m3, const float* v3,
    float* __restrict__ sc, float* __restrict__ sh) {
    int i = blockIdx.x * blockDim.x + threadIdx.x;
    if (i >= 3 * DH) return;
    int l = i >> 7, c = i & (DH - 1);
    const float* bc = l == 0 ? b1 : (l == 1 ? b2 : b3);
    const float* g  = l == 0 ? g1 : (l == 1 ? g2 : g3);
    const float* bb = l == 0 ? bb1 : (l == 1 ? bb2 : bb3);
    const float* m  = l == 0 ? m1 : (l == 1 ? m2 : m3);
    const float* v  = l == 0 ? v1 : (l == 1 ? v2 : v3);
    float s = g[c] * rsqrtf(v[c] + EPS_BN);
    sc[i] = s;
    sh[i] = (bc[c] - m[c]) * s + bb[c];
}

// ============ FUSED LAYER: agg(H) -> LDS (swizzled bf16) -> MFMA @ Wt -> BN+ReLU [+res] ============
// conv(h) = agg(h) @ W + b  (linearity). Block = 64 rows, 256 threads (4 waves).
// Phase 1: 16 groups x 16 lanes; group g aggregates rows g*4..g*4+3 (fp32 acc, bf16 store).
// LDS chunk-XOR swizzle (c ^= row&7) -> phase-2 ds_read_b128 is 2-way (free).
// Phase 2: wave w rows w*16..w*16+15; A from LDS, B=Wt[128][K] from global (L1-hot).
template <int K, bool RES>
__global__ __launch_bounds__(256) void layer_kernel(const u16* __restrict__ H,      // [n][K]
                                                    const u16* __restrict__ Hres,   // [n][DH]
                                                    const u64* __restrict__ colval,
                                                    const int* __restrict__ row_ptr,
                                                    const float* __restrict__ dis,
                                                    const u16* __restrict__ Wt,     // [DH][K]
                                                    const float* __restrict__ scl,
                                                    const float* __restrict__ shf,
                                                    u16* __restrict__ out, int n) { // [n][DH]
    constexpr int EL = K / 16;            // elems per lane in gather: 4 (K=64) / 8 (K=128)
    __shared__ u16 lds_a[64 * K];

    const int tid = threadIdx.x;
    const int g   = tid >> 4;
    const int cl  = tid & 15;
    const long base = (long)blockIdx.x * 64;

    // ---------- phase 1: aggregate ----------
    for (int rr = 0; rr < 4; ++rr) {
        const int r_loc = g * 4 + rr;
        const long i = base + r_loc;
        float acc[EL];
#pragma unroll
        for (int q = 0; q < EL; ++q) acc[q] = 0.0f;
        if (i < n) {
            float d2 = dis[i];
            d2 *= d2;
            if constexpr (EL == 8) {
                const s16x8 hv = *(const s16x8*)(H + i * K + cl * 8);
#pragma unroll
                for (int q = 0; q < 8; ++q) acc[q] = bf2f((u16)hv[q]) * d2;
            } else {
                const s16x4 hv = *(const s16x4*)(H + i * K + cl * 4);
#pragma unroll
                for (int q = 0; q < 4; ++q) acc[q] = bf2f((u16)hv[q]) * d2;
            }
            const int beg = row_ptr[i];
            const int end = row_ptr[i + 1];
            for (int e = beg; e < end; ++e) {
                const u64 cv = colval[e];
                const int s = (int)(unsigned)cv;
                const float nm = __builtin_bit_cast(float, (unsigned)(cv >> 32));
                if constexpr (EL == 8) {
                    const s16x8 v = *(const s16x8*)(H + (long)s * K + cl * 8);
#pragma unroll
                    for (int q = 0; q < 8; ++q) acc[q] = fmaf(bf2f((u16)v[q]), nm, acc[q]);
                } else {
                    const s16x4 v = *(const s16x4*)(H + (long)s * K + cl * 4);
#pragma unroll
                    for (int q = 0; q < 4; ++q) acc[q] = fmaf(bf2f((u16)v[q]), nm, acc[q]);
                }
            }
        }
        if constexpr (EL == 8) {
            const int cs = cl ^ (r_loc & 7);
            s16x8 ov;
#pragma unroll
            for (int q = 0; q < 8; ++q) ov[q] = (short)f2bf(acc[q]);
            *(s16x8*)&lds_a[r_loc * K + cs * 8] = ov;
        } else {
            const int cs = (cl >> 1) ^ (r_loc & 7);
            s16x4 ov;
#pragma unroll
            for (int q = 0; q < 4; ++q) ov[q] = (short)f2bf(acc[q]);
            *(s16x4*)&lds_a[r_loc * K + cs * 8 + (cl & 1) * 4] = ov;
        }
    }
    __syncthreads();

    // ---------- phase 2: MFMA + epilogue ----------
    const int wave = tid >> 6;
    const int lane = tid & 63;
    const int r16 = lane & 15;
    const int kc  = lane >> 4;
    const int rl  = wave * 16 + r16;

    f32x4 acc2[8];
#pragma unroll
    for (int t = 0; t < 8; ++t)
#pragma unroll
        for (int q = 0; q < 4; ++q) acc2[t][q] = 0.0f;

#pragma unroll
    for (int ks = 0; ks < K / 32; ++ks) {
        const int cs = (kc + ks * 4) ^ (rl & 7);
        const s16x8 a = *(const s16x8*)&lds_a[rl * K + cs * 8];
#pragma unroll
        for (int t = 0; t < 8; ++t) {
            const s16x8 b = *(const s16x8*)(Wt + (long)(t * 16 + r16) * K + ks * 32 + kc * 8);
            acc2[t] = __builtin_amdgcn_mfma_f32_16x16x32_bf16(a, b, acc2[t], 0, 0, 0);
        }
    }

    float scv[8], shv[8];
#pragma unroll
    for (int t = 0; t < 8; ++t) {
        scv[t] = scl[t * 16 + r16];
        shv[t] = shf[t * 16 + r16];
    }

#pragma unroll
    for (int q = 0; q < 4; ++q) {
        const long row = base + wave * 16 + kc * 4 + q;
        if (row < n) {
            u16* op = out + row * DH + r16;
            const u16* rp = Hres + row * DH + r16;
#pragma unroll
            for (int t = 0; t < 8; ++t) {
                float y = fmaxf(fmaf(acc2[t][q], scv[t], shv[t]), 0.0f);
                if (RES) y += bf2f(rp[t * 16]);
                op[t * 16] = f2bf(y);
            }
        }
    }
}

// ---------------- per-graph boundaries ----------------
__global__ __launch_bounds__(256) void graph_bounds_kernel(const int* __restrict__ batch,
                                                           int* __restrict__ gp) {
    int g = blockIdx.x * blockDim.x + threadIdx.x;
    if (g > NG) return;
    int lo = 0, hi = N_NODES;
    while (lo < hi) {
        int mid = (lo + hi) >> 1;
        if (batch[mid] < g) lo = mid + 1; else hi = mid;
    }
    gp[g] = lo;
}

// ------- segmented mean pool: 1 block/graph, 16 node-subgroups x 16 lanes, LDS reduce -------
__global__ __launch_bounds__(256) void pool_kernel(const u16* __restrict__ h,
                                                   const int* __restrict__ gp,
                                                   float* __restrict__ pooled) {
    const int g = blockIdx.x;
    const int t = threadIdx.x;
    const int grp = t >> 4;
    const int cl = t & 15;
    const int c = cl * 8;
    const int beg = gp[g];
    const int end = gp[g + 1];

    float acc[8] = {0, 0, 0, 0, 0, 0, 0, 0};
    for (int i = beg + grp; i < end; i += 16) {
        const s16x8 v = *(const s16x8*)(h + (long)i * DH + c);
#pragma unroll
        for (int q = 0; q < 8; ++q) acc[q] += bf2f((u16)v[q]);
    }

    __shared__ float sm[16][DH];
#pragma unroll
    for (int q = 0; q < 8; ++q) sm[grp][c + q] = acc[q];
    __syncthreads();

    if (t < DH) {
        float s = 0.0f;
#pragma unroll
        for (int r = 0; r < 16; ++r) s += sm[r][t];
        pooled[(long)g * DH + t] = s / fmaxf((float)(end - beg), 1.0f);
    }
}

// ---------------- MLP head ----------------
__global__ __launch_bounds__(64) void head_kernel(const float* __restrict__ pooled,
                                                  const float* __restrict__ fc1w,
                                                  const float* __restrict__ fc1b,
                                                  const float* __restrict__ fc2w,
                                                  const float* __restrict__ fc2b,
                                                  float* __restrict__ out) {
    const int g = blockIdx.x;
    const int j = threadIdx.x;
    __shared__ float p[DH];
    p[j]      = pooled[(long)g * DH + j];
    p[j + 64] = pooled[(long)g * DH + 64 + j];
    __syncthreads();

    float acc = 0.0f;
#pragma unroll 4
    for (int k = 0; k < DH; ++k) acc = fmaf(p[k], fc1w[(long)k * 64 + j], acc);
    const float h1 = fmaxf(acc + fc1b[j], 0.0f);
    float v = h1 * fc2w[j];
#pragma unroll
    for (int off = 32; off > 0; off >>= 1) v += __shfl_down(v, off);
    if (j == 0) out[g] = 1.0f / (1.0f + expf(-(v + fc2b[0])));
}

// ---------------- launch ----------------
extern "C" void kernel_launch(void* const* d_in, const int* in_sizes, int n_in,
                              void* d_out, int out_size, void* d_ws, size_t ws_size,
                              hipStream_t stream) {
    const float* x     = (const float*)d_in[0];
    const int*   ei    = (const int*)d_in[1];
    const int*   batch = (const int*)d_in[2];
    const float* W1 = (const float*)d_in[3];
    const float* b1 = (const float*)d_in[4];
    const float* g1 = (const float*)d_in[5];
    const float* t1 = (const float*)d_in[6];
    const float* m1 = (const float*)d_in[7];
    const float* v1 = (const float*)d_in[8];
    const float* W2 = (const float*)d_in[9];
    const float* b2 = (const float*)d_in[10];
    const float* g2 = (const float*)d_in[11];
    const float* t2 = (const float*)d_in[12];
    const float* m2 = (const float*)d_in[13];
    const float* v2 = (const float*)d_in[14];
    const float* W3 = (const float*)d_in[15];
    const float* b3 = (const float*)d_in[16];
    const float* g3 = (const float*)d_in[17];
    const float* t3 = (const float*)d_in[18];
    const float* m3 = (const float*)d_in[19];
    const float* v3 = (const float*)d_in[20];
    const float* fc1w = (const float*)d_in[21];
    const float* fc1b = (const float*)d_in[22];
    const float* fc2w = (const float*)d_in[23];
    const float* fc2b = (const float*)d_in[24];

    const int* src = ei;
    const int* dst = ei + N_EDGES;

    // ---- workspace ----
    char* ws = (char*)d_ws;
    size_t off = 0;
    auto alloc = [&](size_t bytes) -> char* {
        char* p = ws + off;
        off = (off + bytes + 511) & ~(size_t)511;
        return p;
    };
    // deg & cursor adjacent -> one memset clears both
    float* deg     = (float*)alloc((size_t)2 * N_NODES * 4);
    int*   cursor  = (int*)(deg + N_NODES);
    float* dis     = (float*)alloc((size_t)N_NODES * 4);
    int*   deg_i   = (int*)  alloc((size_t)N_NODES * 4);
    int*   row_ptr = (int*)  alloc(((size_t)N_NODES + 1) * 4);
    int*   blk     = (int*)  alloc((size_t)N_SCAN_BLK * 4);
    u64*   colval  = (u64*)  alloc((size_t)N_EDGES * 8);
    int*   gp      = (int*)  alloc((size_t)(NG + 1) * 4);
    float* pooled  = (float*)alloc((size_t)NG * DH * 4);
    float* bnsc    = (float*)alloc((size_t)3 * DH * 4);
    float* bnsh    = (float*)alloc((size_t)3 * DH * 4);
    u16*   xb      = (u16*)  alloc((size_t)N_NODES * DIN * 2);
    u16*   Wt1     = (u16*)  alloc((size_t)DH * DIN * 2);
    u16*   Wt2     = (u16*)  alloc((size_t)DH * DH * 2);
    u16*   Wt3     = (u16*)  alloc((size_t)DH * DH * 2);
    u16*   buf1    = (u16*)  alloc((size_t)N_NODES * DH * 2);
    u16*   buf2    = (u16*)  alloc((size_t)N_NODES * DH * 2);

    const int TPB = 256;
    const int gEdge  = (N_EDGES + TPB - 1) / TPB;
    const int gNode  = (N_NODES + TPB - 1) / TPB;
    const int gLayer = (N_NODES + 63) / 64;   // 1563

    // ---- prep ----
    hipMemsetAsync(deg, 0, (size_t)2 * N_NODES * 4, stream);
    deg_kernel<<<gEdge, TPB, 0, stream>>>(dst, deg, N_EDGES);
    dis_kernel<<<gNode, TPB, 0, stream>>>(deg, dis, deg_i, N_NODES);
    scan1_kernel<<<N_SCAN_BLK, SCAN_TPB, 0, stream>>>(deg_i, row_ptr, blk, N_NODES);
    scan2_kernel<<<1, 512, 0, stream>>>(blk, row_ptr, N_SCAN_BLK, N_NODES);
    scan3_kernel<<<N_SCAN_BLK, SCAN_TPB, 0, stream>>>(row_ptr, blk, N_NODES);
    build_csr_kernel<<<gEdge, TPB, 0, stream>>>(src, dst, dis, row_ptr, cursor, colval,
                                                N_EDGES);
    graph_bounds_kernel<<<3, 256, 0, stream>>>(batch, gp);

    xcvt_kernel<<<(int)(((long)N_NODES * DIN / 8 + TPB - 1) / TPB), TPB, 0, stream>>>(
        x, xb, (long)N_NODES * DIN);
    wt_kernel<<<(DIN * DH + TPB - 1) / TPB, TPB, 0, stream>>>(W1, Wt1, DIN, DH);
    wt_kernel<<<(DH * DH + TPB - 1) / TPB, TPB, 0, stream>>>(W2, Wt2, DH, DH);
    wt_kernel<<<(DH * DH + TPB - 1) / TPB, TPB, 0, stream>>>(W3, Wt3, DH, DH);
    bn_prep_kernel<<<2, TPB, 0, stream>>>(b1, g1, t1, m1, v1, b2, g2, t2, m2, v2,
                                          b3, g3, t3, m3, v3, bnsc, bnsh);

    // ---- fused layers (agg -> gemm -> bn/relu) ----
    layer_kernel<DIN, false><<<gLayer, TPB, 0, stream>>>(xb, xb, colval, row_ptr, dis,
                                                         Wt1, bnsc, bnsh, buf1, N_NODES);
    layer_kernel<DH, true><<<gLayer, TPB, 0, stream>>>(buf1, buf1, colval, row_ptr, dis,
                                                       Wt2, bnsc + DH, bnsh + DH, buf2,
                                                       N_NODES);
    layer_kernel<DH, false><<<gLayer, TPB, 0, stream>>>(buf2, buf2, colval, row_ptr, dis,
                                                        Wt3, bnsc + 2 * DH, bnsh + 2 * DH,
                                                        buf1, N_NODES);

    // ---- pool + head ----
    pool_kernel<<<NG, TPB, 0, stream>>>(buf1, gp, pooled);
    head_kernel<<<NG, 64, 0, stream>>>(pooled, fc1w, fc1b, fc2w, fc2b, (float*)d_out);
}

// Round 7
// 310.264 us; speedup vs baseline: 1.1269x; 1.1269x over previous
//
#include <hip/hip_runtime.h>
#include <math.h>

#define N_NODES 100000
#define N_EDGES 600000
#define DIN     64
#define DH      128
#define NG      512
#define EPS_BN  1e-5f
#define SCAN_TPB 256
#define N_SCAN_BLK ((N_NODES + SCAN_TPB - 1) / SCAN_TPB)   // 391

typedef unsigned short u16;
typedef unsigned long long u64;
typedef short s16x8 __attribute__((ext_vector_type(8)));
typedef float f32x4 __attribute__((ext_vector_type(4)));

__device__ __forceinline__ u16 f2bf(float x) {
    unsigned u = __builtin_bit_cast(unsigned, x);
    u += 0x7fffu + ((u >> 16) & 1u);   // round-to-nearest-even
    return (u16)(u >> 16);
}
__device__ __forceinline__ float bf2f(u16 h) {
    unsigned u = ((unsigned)h) << 16;
    return __builtin_bit_cast(float, u);
}

// ---------------- degree histogram ----------------
__global__ __launch_bounds__(256) void deg_kernel(const int* __restrict__ dst,
                                                  float* __restrict__ deg, int E) {
    int e = blockIdx.x * blockDim.x + threadIdx.x;
    if (e < E) atomicAdd(&deg[dst[e]], 1.0f);
}

__global__ __launch_bounds__(256) void dis_kernel(const float* __restrict__ deg,
                                                  float* __restrict__ dis,
                                                  int* __restrict__ deg_i, int n) {
    int i = blockIdx.x * blockDim.x + threadIdx.x;
    if (i < n) {
        float d = deg[i];
        dis[i] = rsqrtf(d + 1.0f);   // +1 self loop
        deg_i[i] = (int)d;
    }
}

// ---------------- multi-block scan ----------------
__global__ __launch_bounds__(SCAN_TPB) void scan1_kernel(const int* __restrict__ deg_i,
                                                         int* __restrict__ row_ptr,
                                                         int* __restrict__ blk, int n) {
    __shared__ int sm[SCAN_TPB];
    const int t = threadIdx.x;
    const int i = blockIdx.x * SCAN_TPB + t;
    const int v = (i < n) ? deg_i[i] : 0;
    sm[t] = v;
    __syncthreads();
#pragma unroll
    for (int off = 1; off < SCAN_TPB; off <<= 1) {
        int u = (t >= off) ? sm[t - off] : 0;
        __syncthreads();
        sm[t] += u;
        __syncthreads();
    }
    if (i < n) row_ptr[i] = sm[t] - v;
    if (t == SCAN_TPB - 1) blk[blockIdx.x] = sm[t];
}

__global__ __launch_bounds__(512) void scan2_kernel(int* __restrict__ blk,
                                                    int* __restrict__ row_ptr,
                                                    int nblk, int n) {
    __shared__ int sm[512];
    const int t = threadIdx.x;
    const int v = (t < nblk) ? blk[t] : 0;
    sm[t] = v;
    __syncthreads();
#pragma unroll
    for (int off = 1; off < 512; off <<= 1) {
        int u = (t >= off) ? sm[t - off] : 0;
        __syncthreads();
        sm[t] += u;
        __syncthreads();
    }
    if (t < nblk) blk[t] = sm[t] - v;
    if (t == nblk - 1) row_ptr[n] = sm[t];
}

__global__ __launch_bounds__(SCAN_TPB) void scan3_kernel(int* __restrict__ row_ptr,
                                                         const int* __restrict__ blk, int n) {
    const int i = blockIdx.x * SCAN_TPB + threadIdx.x;
    if (i < n) row_ptr[i] += blk[blockIdx.x];
}

// ---------------- scatter edges into CSR: packed (val<<32 | col), single 8B store ----------------
__global__ __launch_bounds__(256) void build_csr_kernel(const int* __restrict__ src,
                                                        const int* __restrict__ dst,
                                                        const float* __restrict__ dis,
                                                        const int* __restrict__ row_ptr,
                                                        int* __restrict__ cursor,
                                                        u64* __restrict__ colval, int E) {
    int e = blockIdx.x * blockDim.x + threadIdx.x;
    if (e >= E) return;
    const int s = src[e];
    const int d = dst[e];
    const int p = atomicAdd(&cursor[d], 1);
    const unsigned fb = __builtin_bit_cast(unsigned, dis[s] * dis[d]);
    colval[row_ptr[d] + p] = ((u64)fb << 32) | (unsigned)s;
}

// ------- merged prep: xcvt | Wt1 | Wt2 | Wt3 | bn fold | graph bounds (range dispatch) -------
#define PREP_XCVT_BLKS 3125          // 100000*64/8/256
#define PREP_WT1_BLKS  32            // 64*128/256
#define PREP_WT2_BLKS  64            // 128*128/256
#define PREP_WT3_BLKS  64
#define PREP_BN_BLKS   2
#define PREP_GB_BLKS   3
#define PREP_B0 PREP_XCVT_BLKS
#define PREP_B1 (PREP_B0 + PREP_WT1_BLKS)
#define PREP_B2 (PREP_B1 + PREP_WT2_BLKS)
#define PREP_B3 (PREP_B2 + PREP_WT3_BLKS)
#define PREP_B4 (PREP_B3 + PREP_BN_BLKS)
#define PREP_TOTAL (PREP_B4 + PREP_GB_BLKS)

__device__ __forceinline__ void wt_body(const float* __restrict__ W, u16* __restrict__ Wt,
                                        int K, int idx) {
    if (idx >= K * DH) return;
    int k = idx / DH, n = idx % DH;
    Wt[(long)n * K + k] = f2bf(W[idx]);
}

__global__ __launch_bounds__(256) void prep_kernel(
    const float* __restrict__ x, u16* __restrict__ xb,
    const float* __restrict__ W1, u16* __restrict__ Wt1,
    const float* __restrict__ W2, u16* __restrict__ Wt2,
    const float* __restrict__ W3, u16* __restrict__ Wt3,
    const float* b1, const float* g1, const float* bb1, const float* m1, const float* v1,
    const float* b2, const float* g2, const float* bb2, const float* m2, const float* v2,
    const float* b3, const float* g3, const float* bb3, const float* m3, const float* v3,
    float* __restrict__ sc, float* __restrict__ sh,
    const int* __restrict__ batch, int* __restrict__ gp) {
    const int b = blockIdx.x;
    const int tid = threadIdx.x;
    if (b < PREP_B0) {
        const long i = ((long)b * 256 + tid) * 8;
        const float4 a = *(const float4*)(x + i);
        const float4 c = *(const float4*)(x + i + 4);
        s16x8 o;
        o[0] = (short)f2bf(a.x); o[1] = (short)f2bf(a.y);
        o[2] = (short)f2bf(a.z); o[3] = (short)f2bf(a.w);
        o[4] = (short)f2bf(c.x); o[5] = (short)f2bf(c.y);
        o[6] = (short)f2bf(c.z); o[7] = (short)f2bf(c.w);
        *(s16x8*)(xb + i) = o;
    } else if (b < PREP_B1) {
        wt_body(W1, Wt1, DIN, (b - PREP_B0) * 256 + tid);
    } else if (b < PREP_B2) {
        wt_body(W2, Wt2, DH, (b - PREP_B1) * 256 + tid);
    } else if (b < PREP_B3) {
        wt_body(W3, Wt3, DH, (b - PREP_B2) * 256 + tid);
    } else if (b < PREP_B4) {
        const int i = (b - PREP_B3) * 256 + tid;
        if (i < 3 * DH) {
            int l = i >> 7, c = i & (DH - 1);
            const float* bc = l == 0 ? b1 : (l == 1 ? b2 : b3);
            const float* g  = l == 0 ? g1 : (l == 1 ? g2 : g3);
            const float* bb = l == 0 ? bb1 : (l == 1 ? bb2 : bb3);
            const float* m  = l == 0 ? m1 : (l == 1 ? m2 : m3);
            const float* v  = l == 0 ? v1 : (l == 1 ? v2 : v3);
            float s = g[c] * rsqrtf(v[c] + EPS_BN);
            sc[i] = s;
            sh[i] = (bc[c] - m[c]) * s + bb[c];
        }
    } else {
        const int g = (b - PREP_B4) * 256 + tid;
        if (g <= NG) {
            int lo = 0, hi = N_NODES;
            while (lo < hi) {
                int mid = (lo + hi) >> 1;
                if (batch[mid] < g) lo = mid + 1; else hi = mid;
            }
            gp[g] = lo;
        }
    }
}

// ---------------- MFMA GEMM: C[M,128] = A[M,K] @ Wt^T, bf16 in/out, fp32 acc ----------------
template <int K>
__global__ __launch_bounds__(256) void gemm_mfma(const u16* __restrict__ A,   // [M][K] bf16
                                                 const u16* __restrict__ Wt,  // [128][K] bf16
                                                 u16* __restrict__ C,         // [M][128] bf16
                                                 int M) {
    const int wave = threadIdx.x >> 6;
    const int lane = threadIdx.x & 63;
    const int r16 = lane & 15;
    const int kc  = lane >> 4;
    const long row0 = (long)blockIdx.x * 64 + wave * 16;

    f32x4 acc[8];
#pragma unroll
    for (int t = 0; t < 8; ++t)
#pragma unroll
        for (int q = 0; q < 4; ++q) acc[t][q] = 0.0f;

    long arow = row0 + r16;
    if (arow >= M) arow = M - 1;
    const u16* ap = A + arow * K + kc * 8;

#pragma unroll
    for (int ks = 0; ks < K; ks += 32) {
        const s16x8 a = *(const s16x8*)(ap + ks);
#pragma unroll
        for (int t = 0; t < 8; ++t) {
            const s16x8 b = *(const s16x8*)(Wt + (long)(t * 16 + r16) * K + ks + kc * 8);
            acc[t] = __builtin_amdgcn_mfma_f32_16x16x32_bf16(a, b, acc[t], 0, 0, 0);
        }
    }

#pragma unroll
    for (int r = 0; r < 4; ++r) {
        const long row = row0 + kc * 4 + r;
        if (row < M) {
            u16* cp = C + row * DH + r16;
#pragma unroll
            for (int t = 0; t < 8; ++t) cp[t * 16] = f2bf(acc[t][r]);
        }
    }
}

// ---- fused: CSR gather-sum (2-way edge-parallel) + selfloop + BN + ReLU [+res], bf16 ----
// 32 lanes/node: cl = lane&15 -> channel chunk, eh = lane>>4 -> edge slot (0/1).
template <bool RES>
__global__ __launch_bounds__(256) void agg_epi_kernel(const u16* __restrict__ H,
                                                      const int* __restrict__ row_ptr,
                                                      const u64* __restrict__ colval,
                                                      const float* __restrict__ dis,
                                                      const float* __restrict__ scl,
                                                      const float* __restrict__ shf,
                                                      u16* __restrict__ out, int n) {
    const long t = (long)blockIdx.x * blockDim.x + threadIdx.x;
    const int lane = (int)(t & 31);
    const long i = t >> 5;
    if (i >= n) return;
    const int cl = lane & 15;
    const int eh = lane >> 4;
    const int c = cl * 8;

    float acc[8] = {0, 0, 0, 0, 0, 0, 0, 0};
    if (eh == 0) {
        float d2 = dis[i];
        d2 *= d2;
        const s16x8 hv = *(const s16x8*)(H + i * DH + c);
#pragma unroll
        for (int q = 0; q < 8; ++q) acc[q] = bf2f((u16)hv[q]) * d2;   // self-loop
    }

    const int beg = row_ptr[i];
    const int end = row_ptr[i + 1];
    for (int e = beg + eh; e < end; e += 2) {
        const u64 cv = colval[e];
        const int s = (int)(unsigned)cv;
        const float nm = __builtin_bit_cast(float, (unsigned)(cv >> 32));
        const s16x8 v = *(const s16x8*)(H + (long)s * DH + c);
#pragma unroll
        for (int q = 0; q < 8; ++q) acc[q] = fmaf(bf2f((u16)v[q]), nm, acc[q]);
    }

    // combine the two edge slots (lanes L and L^16 within the wave)
#pragma unroll
    for (int q = 0; q < 8; ++q) acc[q] += __shfl_xor(acc[q], 16);

    if (eh == 0) {
        const float4 s0 = *(const float4*)(scl + c);
        const float4 s1 = *(const float4*)(scl + c + 4);
        const float4 f0 = *(const float4*)(shf + c);
        const float4 f1 = *(const float4*)(shf + c + 4);
        const float sv[8] = {s0.x, s0.y, s0.z, s0.w, s1.x, s1.y, s1.z, s1.w};
        const float fv[8] = {f0.x, f0.y, f0.z, f0.w, f1.x, f1.y, f1.z, f1.w};

        float r[8];
#pragma unroll
        for (int q = 0; q < 8; ++q) r[q] = fmaxf(fmaf(acc[q], sv[q], fv[q]), 0.0f);
        if (RES) {
            const s16x8 rv = *(const s16x8*)(out + i * DH + c);
#pragma unroll
            for (int q = 0; q < 8; ++q) r[q] += bf2f((u16)rv[q]);
        }
        s16x8 ov;
#pragma unroll
        for (int q = 0; q < 8; ++q) ov[q] = (short)f2bf(r[q]);
        *(s16x8*)(out + i * DH + c) = ov;
    }
}

// ------- segmented mean pool: 1 block/graph, 16 node-subgroups x 16 lanes, LDS reduce -------
__global__ __launch_bounds__(256) void pool_kernel(const u16* __restrict__ h,
                                                   const int* __restrict__ gp,
                                                   float* __restrict__ pooled) {
    const int g = blockIdx.x;
    const int t = threadIdx.x;
    const int grp = t >> 4;
    const int cl = t & 15;
    const int c = cl * 8;
    const int beg = gp[g];
    const int end = gp[g + 1];

    float acc[8] = {0, 0, 0, 0, 0, 0, 0, 0};
    for (int i = beg + grp; i < end; i += 16) {
        const s16x8 v = *(const s16x8*)(h + (long)i * DH + c);
#pragma unroll
        for (int q = 0; q < 8; ++q) acc[q] += bf2f((u16)v[q]);
    }

    __shared__ float sm[16][DH];
#pragma unroll
    for (int q = 0; q < 8; ++q) sm[grp][c + q] = acc[q];
    __syncthreads();

    if (t < DH) {
        float s = 0.0f;
#pragma unroll
        for (int r = 0; r < 16; ++r) s += sm[r][t];
        pooled[(long)g * DH + t] = s / fmaxf((float)(end - beg), 1.0f);
    }
}

// ---------------- MLP head ----------------
__global__ __launch_bounds__(64) void head_kernel(const float* __restrict__ pooled,
                                                  const float* __restrict__ fc1w,
                                                  const float* __restrict__ fc1b,
                                                  const float* __restrict__ fc2w,
                                                  const float* __restrict__ fc2b,
                                                  float* __restrict__ out) {
    const int g = blockIdx.x;
    const int j = threadIdx.x;
    __shared__ float p[DH];
    p[j]      = pooled[(long)g * DH + j];
    p[j + 64] = pooled[(long)g * DH + 64 + j];
    __syncthreads();

    float acc = 0.0f;
#pragma unroll 4
    for (int k = 0; k < DH; ++k) acc = fmaf(p[k], fc1w[(long)k * 64 + j], acc);
    const float h1 = fmaxf(acc + fc1b[j], 0.0f);
    float v = h1 * fc2w[j];
#pragma unroll
    for (int off = 32; off > 0; off >>= 1) v += __shfl_down(v, off);
    if (j == 0) out[g] = 1.0f / (1.0f + expf(-(v + fc2b[0])));
}

// ---------------- launch ----------------
extern "C" void kernel_launch(void* const* d_in, const int* in_sizes, int n_in,
                              void* d_out, int out_size, void* d_ws, size_t ws_size,
                              hipStream_t stream) {
    const float* x     = (const float*)d_in[0];
    const int*   ei    = (const int*)d_in[1];
    const int*   batch = (const int*)d_in[2];
    const float* W1 = (const float*)d_in[3];
    const float* b1 = (const float*)d_in[4];
    const float* g1 = (const float*)d_in[5];
    const float* t1 = (const float*)d_in[6];
    const float* m1 = (const float*)d_in[7];
    const float* v1 = (const float*)d_in[8];
    const float* W2 = (const float*)d_in[9];
    const float* b2 = (const float*)d_in[10];
    const float* g2 = (const float*)d_in[11];
    const float* t2 = (const float*)d_in[12];
    const float* m2 = (const float*)d_in[13];
    const float* v2 = (const float*)d_in[14];
    const float* W3 = (const float*)d_in[15];
    const float* b3 = (const float*)d_in[16];
    const float* g3 = (const float*)d_in[17];
    const float* t3 = (const float*)d_in[18];
    const float* m3 = (const float*)d_in[19];
    const float* v3 = (const float*)d_in[20];
    const float* fc1w = (const float*)d_in[21];
    const float* fc1b = (const float*)d_in[22];
    const float* fc2w = (const float*)d_in[23];
    const float* fc2b = (const float*)d_in[24];

    const int* src = ei;
    const int* dst = ei + N_EDGES;

    // ---- workspace ----
    char* ws = (char*)d_ws;
    size_t off = 0;
    auto alloc = [&](size_t bytes) -> char* {
        char* p = ws + off;
        off = (off + bytes + 511) & ~(size_t)511;
        return p;
    };
    // deg & cursor adjacent -> one memset clears both
    float* deg     = (float*)alloc((size_t)2 * N_NODES * 4);
    int*   cursor  = (int*)(deg + N_NODES);
    float* dis     = (float*)alloc((size_t)N_NODES * 4);
    int*   deg_i   = (int*)  alloc((size_t)N_NODES * 4);
    int*   row_ptr = (int*)  alloc(((size_t)N_NODES + 1) * 4);
    int*   blk     = (int*)  alloc((size_t)N_SCAN_BLK * 4);
    u64*   colval  = (u64*)  alloc((size_t)N_EDGES * 8);
    int*   gp      = (int*)  alloc((size_t)(NG + 1) * 4);
    float* pooled  = (float*)alloc((size_t)NG * DH * 4);
    float* bnsc    = (float*)alloc((size_t)3 * DH * 4);
    float* bnsh    = (float*)alloc((size_t)3 * DH * 4);
    u16*   xb      = (u16*)  alloc((size_t)N_NODES * DIN * 2);
    u16*   Wt1     = (u16*)  alloc((size_t)DH * DIN * 2);
    u16*   Wt2     = (u16*)  alloc((size_t)DH * DH * 2);
    u16*   Wt3     = (u16*)  alloc((size_t)DH * DH * 2);
    u16*   bufB    = (u16*)  alloc((size_t)N_NODES * DH * 2);
    u16*   bufA    = (u16*)  alloc((size_t)N_NODES * DH * 2);

    const int TPB = 256;
    const int gEdge  = (N_EDGES + TPB - 1) / TPB;
    const int gNode  = (N_NODES + TPB - 1) / TPB;
    const int gGemm  = (N_NODES + 63) / 64;                               // 1563
    const int gAgg   = (int)(((long)N_NODES * 32 + TPB - 1) / TPB);       // 12500

    // ---- graph structure prep ----
    hipMemsetAsync(deg, 0, (size_t)2 * N_NODES * 4, stream);
    deg_kernel<<<gEdge, TPB, 0, stream>>>(dst, deg, N_EDGES);
    dis_kernel<<<gNode, TPB, 0, stream>>>(deg, dis, deg_i, N_NODES);
    scan1_kernel<<<N_SCAN_BLK, SCAN_TPB, 0, stream>>>(deg_i, row_ptr, blk, N_NODES);
    scan2_kernel<<<1, 512, 0, stream>>>(blk, row_ptr, N_SCAN_BLK, N_NODES);
    scan3_kernel<<<N_SCAN_BLK, SCAN_TPB, 0, stream>>>(row_ptr, blk, N_NODES);
    build_csr_kernel<<<gEdge, TPB, 0, stream>>>(src, dst, dis, row_ptr, cursor, colval,
                                                N_EDGES);
    prep_kernel<<<PREP_TOTAL, TPB, 0, stream>>>(x, xb, W1, Wt1, W2, Wt2, W3, Wt3,
                                                b1, g1, t1, m1, v1,
                                                b2, g2, t2, m2, v2,
                                                b3, g3, t3, m3, v3,
                                                bnsc, bnsh, batch, gp);

    // ---- layer 1 ----
    gemm_mfma<DIN><<<gGemm, TPB, 0, stream>>>(xb, Wt1, bufB, N_NODES);
    agg_epi_kernel<false><<<gAgg, TPB, 0, stream>>>(bufB, row_ptr, colval, dis,
                                                    bnsc, bnsh, bufA, N_NODES);
    // ---- layer 2 (residual, in-place on bufA) ----
    gemm_mfma<DH><<<gGemm, TPB, 0, stream>>>(bufA, Wt2, bufB, N_NODES);
    agg_epi_kernel<true><<<gAgg, TPB, 0, stream>>>(bufB, row_ptr, colval, dis,
                                                   bnsc + DH, bnsh + DH, bufA, N_NODES);
    // ---- layer 3 ----
    gemm_mfma<DH><<<gGemm, TPB, 0, stream>>>(bufA, Wt3, bufB, N_NODES);
    agg_epi_kernel<false><<<gAgg, TPB, 0, stream>>>(bufB, row_ptr, colval, dis,
                                                    bnsc + 2 * DH, bnsh + 2 * DH, bufA,
                                                    N_NODES);

    // ---- pool + head ----
    pool_kernel<<<NG, TPB, 0, stream>>>(bufA, gp, pooled);
    head_kernel<<<NG, 64, 0, stream>>>(pooled, fc1w, fc1b, fc2w, fc2b, (float*)d_out);
}

// Round 8
// 295.000 us; speedup vs baseline: 1.1852x; 1.0517x over previous
//
#include <hip/hip_runtime.h>
#include <math.h>

#define N_NODES 100000
#define N_EDGES 600000
#define DIN     64
#define DH      128
#define NG      512
#define EPS_BN  1e-5f
#define SCAN_TPB 256
#define N_SCAN_BLK ((N_NODES + SCAN_TPB - 1) / SCAN_TPB)   // 391
#define G_EDGE   ((N_EDGES + 255) / 256)                   // 2344

typedef unsigned short u16;
typedef short s16x8 __attribute__((ext_vector_type(8)));
typedef float f32x4 __attribute__((ext_vector_type(4)));

__device__ __forceinline__ u16 f2bf(float x) {
    unsigned u = __builtin_bit_cast(unsigned, x);
    u += 0x7fffu + ((u >> 16) & 1u);   // round-to-nearest-even
    return (u16)(u >> 16);
}
__device__ __forceinline__ float bf2f(u16 h) {
    unsigned u = ((unsigned)h) << 16;
    return __builtin_bit_cast(float, u);
}

// ------- merged: degree histogram | xcvt | Wt1..3 | bn fold | graph bounds -------
#define PREP_XCVT_BLKS 3125          // 100000*64/8/256
#define PREP_WT1_BLKS  32
#define PREP_WT2_BLKS  64
#define PREP_WT3_BLKS  64
#define PREP_BN_BLKS   2
#define PREP_GB_BLKS   3
#define PREP_B0 (G_EDGE + PREP_XCVT_BLKS)
#define PREP_B1 (PREP_B0 + PREP_WT1_BLKS)
#define PREP_B2 (PREP_B1 + PREP_WT2_BLKS)
#define PREP_B3 (PREP_B2 + PREP_WT3_BLKS)
#define PREP_B4 (PREP_B3 + PREP_BN_BLKS)
#define PREP_TOTAL (PREP_B4 + PREP_GB_BLKS)

__device__ __forceinline__ void wt_body(const float* __restrict__ W, u16* __restrict__ Wt,
                                        int K, int idx) {
    if (idx >= K * DH) return;
    int k = idx / DH, n = idx % DH;
    Wt[(long)n * K + k] = f2bf(W[idx]);
}

__global__ __launch_bounds__(256) void degprep_kernel(
    const int* __restrict__ dst, int* __restrict__ deg,
    const float* __restrict__ x, u16* __restrict__ xb,
    const float* __restrict__ W1, u16* __restrict__ Wt1,
    const float* __restrict__ W2, u16* __restrict__ Wt2,
    const float* __restrict__ W3, u16* __restrict__ Wt3,
    const float* b1, const float* g1, const float* bb1, const float* m1, const float* v1,
    const float* b2, const float* g2, const float* bb2, const float* m2, const float* v2,
    const float* b3, const float* g3, const float* bb3, const float* m3, const float* v3,
    float* __restrict__ sc, float* __restrict__ sh,
    const int* __restrict__ batch, int* __restrict__ gp) {
    const int b = blockIdx.x;
    const int tid = threadIdx.x;
    if (b < G_EDGE) {
        const int e = b * 256 + tid;
        if (e < N_EDGES) atomicAdd(&deg[dst[e]], 1);
    } else if (b < PREP_B0) {
        const long i = ((long)(b - G_EDGE) * 256 + tid) * 8;
        const float4 a = *(const float4*)(x + i);
        const float4 c = *(const float4*)(x + i + 4);
        s16x8 o;
        o[0] = (short)f2bf(a.x); o[1] = (short)f2bf(a.y);
        o[2] = (short)f2bf(a.z); o[3] = (short)f2bf(a.w);
        o[4] = (short)f2bf(c.x); o[5] = (short)f2bf(c.y);
        o[6] = (short)f2bf(c.z); o[7] = (short)f2bf(c.w);
        *(s16x8*)(xb + i) = o;
    } else if (b < PREP_B1) {
        wt_body(W1, Wt1, DIN, (b - PREP_B0) * 256 + tid);
    } else if (b < PREP_B2) {
        wt_body(W2, Wt2, DH, (b - PREP_B1) * 256 + tid);
    } else if (b < PREP_B3) {
        wt_body(W3, Wt3, DH, (b - PREP_B2) * 256 + tid);
    } else if (b < PREP_B4) {
        const int i = (b - PREP_B3) * 256 + tid;
        if (i < 3 * DH) {
            int l = i >> 7, c = i & (DH - 1);
            const float* bc = l == 0 ? b1 : (l == 1 ? b2 : b3);
            const float* g  = l == 0 ? g1 : (l == 1 ? g2 : g3);
            const float* bb = l == 0 ? bb1 : (l == 1 ? bb2 : bb3);
            const float* m  = l == 0 ? m1 : (l == 1 ? m2 : m3);
            const float* v  = l == 0 ? v1 : (l == 1 ? v2 : v3);
            float s = g[c] * rsqrtf(v[c] + EPS_BN);
            sc[i] = s;
            sh[i] = (bc[c] - m[c]) * s + bb[c];
        }
    } else {
        const int g = (b - PREP_B4) * 256 + tid;
        if (g <= NG) {
            int lo = 0, hi = N_NODES;
            while (lo < hi) {
                int mid = (lo + hi) >> 1;
                if (batch[mid] < g) lo = mid + 1; else hi = mid;
            }
            gp[g] = lo;
        }
    }
}

// ---------------- scan phase 1 (+ dis): local exclusive prefix + block sums ----------------
__global__ __launch_bounds__(SCAN_TPB) void scan1_kernel(const int* __restrict__ deg,
                                                         float* __restrict__ dis,
                                                         int* __restrict__ rp,
                                                         int* __restrict__ blk, int n) {
    __shared__ int sm[SCAN_TPB];
    const int t = threadIdx.x;
    const int i = blockIdx.x * SCAN_TPB + t;
    int v = 0;
    if (i < n) {
        v = deg[i];
        dis[i] = rsqrtf((float)v + 1.0f);   // +1 self loop
    }
    sm[t] = v;
    __syncthreads();
#pragma unroll
    for (int off = 1; off < SCAN_TPB; off <<= 1) {
        int u = (t >= off) ? sm[t - off] : 0;
        __syncthreads();
        sm[t] += u;
        __syncthreads();
    }
    if (i <= n) rp[i] = sm[t] - v;            // local exclusive prefix
    if (t == SCAN_TPB - 1) blk[blockIdx.x] = sm[t];
}

// ---------------- scan phase 2: exclusive scan of block sums (1 block) ----------------
__global__ __launch_bounds__(512) void scan2_kernel(int* __restrict__ blk, int nblk) {
    __shared__ int sm[512];
    const int t = threadIdx.x;
    const int v = (t < nblk) ? blk[t] : 0;
    sm[t] = v;
    __syncthreads();
#pragma unroll
    for (int off = 1; off < 512; off <<= 1) {
        int u = (t >= off) ? sm[t - off] : 0;
        __syncthreads();
        sm[t] += u;
        __syncthreads();
    }
    if (t < nblk) blk[t] = sm[t] - v;         // exclusive prefix of block sums
}

// -------- scatter edges into CSR (col only; row_ptr = rp[d] + blk[d>>8] on the fly) --------
__global__ __launch_bounds__(256) void build_csr_kernel(const int* __restrict__ src,
                                                        const int* __restrict__ dst,
                                                        const int* __restrict__ rp,
                                                        const int* __restrict__ blk,
                                                        int* __restrict__ cursor,
                                                        int* __restrict__ col, int E) {
    int e = blockIdx.x * blockDim.x + threadIdx.x;
    if (e >= E) return;
    const int s = src[e];
    const int d = dst[e];
    const int p = atomicAdd(&cursor[d], 1);
    col[rp[d] + blk[d >> 8] + p] = s;
}

// ---- MFMA GEMM: C[M,128] = (A[M,K] @ Wt^T) * dis[row], bf16 in/out, fp32 acc ----
template <int K>
__global__ __launch_bounds__(256) void gemm_mfma(const u16* __restrict__ A,   // [M][K]
                                                 const u16* __restrict__ Wt,  // [128][K]
                                                 const float* __restrict__ dis,
                                                 u16* __restrict__ C,         // [M][128]
                                                 int M) {
    const int wave = threadIdx.x >> 6;
    const int lane = threadIdx.x & 63;
    const int r16 = lane & 15;
    const int kc  = lane >> 4;
    const long row0 = (long)blockIdx.x * 64 + wave * 16;

    f32x4 acc[8];
#pragma unroll
    for (int t = 0; t < 8; ++t)
#pragma unroll
        for (int q = 0; q < 4; ++q) acc[t][q] = 0.0f;

    long arow = row0 + r16;
    if (arow >= M) arow = M - 1;
    const u16* ap = A + arow * K + kc * 8;

#pragma unroll
    for (int ks = 0; ks < K; ks += 32) {
        const s16x8 a = *(const s16x8*)(ap + ks);
#pragma unroll
        for (int t = 0; t < 8; ++t) {
            const s16x8 b = *(const s16x8*)(Wt + (long)(t * 16 + r16) * K + ks + kc * 8);
            acc[t] = __builtin_amdgcn_mfma_f32_16x16x32_bf16(a, b, acc[t], 0, 0, 0);
        }
    }

#pragma unroll
    for (int r = 0; r < 4; ++r) {
        const long row = row0 + kc * 4 + r;
        if (row < M) {
            const float dd = dis[row];
            u16* cp = C + row * DH + r16;
#pragma unroll
            for (int t = 0; t < 8; ++t) cp[t * 16] = f2bf(acc[t][r] * dd);
        }
    }
}

// ---- fused: agg[d] = dis[d]*(Σ H[col] + H[d]); BN + ReLU [+res]; 2-way edge-parallel ----
template <bool RES>
__global__ __launch_bounds__(256) void agg_epi_kernel(const u16* __restrict__ H,
                                                      const int* __restrict__ rp,
                                                      const int* __restrict__ blk,
                                                      const int* __restrict__ col,
                                                      const float* __restrict__ dis,
                                                      const float* __restrict__ scl,
                                                      const float* __restrict__ shf,
                                                      u16* __restrict__ out, int n) {
    const long t = (long)blockIdx.x * blockDim.x + threadIdx.x;
    const int lane = (int)(t & 31);
    const long i = t >> 5;
    if (i >= n) return;
    const int cl = lane & 15;
    const int eh = lane >> 4;
    const int c = cl * 8;

    float acc[8] = {0, 0, 0, 0, 0, 0, 0, 0};
    if (eh == 0) {   // self row (already pre-scaled by dis[i] in gemm)
        const s16x8 hv = *(const s16x8*)(H + i * DH + c);
#pragma unroll
        for (int q = 0; q < 8; ++q) acc[q] = bf2f((u16)hv[q]);
    }

    const int beg = rp[i] + blk[i >> 8];
    const int end = rp[i + 1] + blk[(int)(i + 1) >> 8];
    for (int e = beg + eh; e < end; e += 2) {
        const int s = col[e];
        const s16x8 v = *(const s16x8*)(H + (long)s * DH + c);
#pragma unroll
        for (int q = 0; q < 8; ++q) acc[q] += bf2f((u16)v[q]);
    }

#pragma unroll
    for (int q = 0; q < 8; ++q) acc[q] += __shfl_xor(acc[q], 16);

    if (eh == 0) {
        const float dd = dis[i];
        const float4 s0 = *(const float4*)(scl + c);
        const float4 s1 = *(const float4*)(scl + c + 4);
        const float4 f0 = *(const float4*)(shf + c);
        const float4 f1 = *(const float4*)(shf + c + 4);
        const float sv[8] = {s0.x, s0.y, s0.z, s0.w, s1.x, s1.y, s1.z, s1.w};
        const float fv[8] = {f0.x, f0.y, f0.z, f0.w, f1.x, f1.y, f1.z, f1.w};

        float r[8];
#pragma unroll
        for (int q = 0; q < 8; ++q) r[q] = fmaxf(fmaf(acc[q] * dd, sv[q], fv[q]), 0.0f);
        if (RES) {
            const s16x8 rv = *(const s16x8*)(out + i * DH + c);
#pragma unroll
            for (int q = 0; q < 8; ++q) r[q] += bf2f((u16)rv[q]);
        }
        s16x8 ov;
#pragma unroll
        for (int q = 0; q < 8; ++q) ov[q] = (short)f2bf(r[q]);
        *(s16x8*)(out + i * DH + c) = ov;
    }
}

// ------- fused mean-pool + MLP head: 1 block/graph -------
__global__ __launch_bounds__(256) void pool_head_kernel(const u16* __restrict__ h,
                                                        const int* __restrict__ gp,
                                                        const float* __restrict__ fc1w,
                                                        const float* __restrict__ fc1b,
                                                        const float* __restrict__ fc2w,
                                                        const float* __restrict__ fc2b,
                                                        float* __restrict__ out) {
    const int g = blockIdx.x;
    const int t = threadIdx.x;
    const int grp = t >> 4;
    const int cl = t & 15;
    const int c = cl * 8;
    const int beg = gp[g];
    const int end = gp[g + 1];

    float acc[8] = {0, 0, 0, 0, 0, 0, 0, 0};
    for (int i = beg + grp; i < end; i += 16) {
        const s16x8 v = *(const s16x8*)(h + (long)i * DH + c);
#pragma unroll
        for (int q = 0; q < 8; ++q) acc[q] += bf2f((u16)v[q]);
    }

    __shared__ float sm[16][DH];
    __shared__ float p[DH];
#pragma unroll
    for (int q = 0; q < 8; ++q) sm[grp][c + q] = acc[q];
    __syncthreads();

    if (t < DH) {
        float s = 0.0f;
#pragma unroll
        for (int r = 0; r < 16; ++r) s += sm[r][t];
        p[t] = s / fmaxf((float)(end - beg), 1.0f);
    }
    __syncthreads();

    if (t < 64) {
        float a = 0.0f;
#pragma unroll 4
        for (int k = 0; k < DH; ++k) a = fmaf(p[k], fc1w[(long)k * 64 + t], a);
        const float h1 = fmaxf(a + fc1b[t], 0.0f);
        float v = h1 * fc2w[t];
#pragma unroll
        for (int off = 32; off > 0; off >>= 1) v += __shfl_down(v, off);
        if (t == 0) out[g] = 1.0f / (1.0f + expf(-(v + fc2b[0])));
    }
}

// ---------------- launch ----------------
extern "C" void kernel_launch(void* const* d_in, const int* in_sizes, int n_in,
                              void* d_out, int out_size, void* d_ws, size_t ws_size,
                              hipStream_t stream) {
    const float* x     = (const float*)d_in[0];
    const int*   ei    = (const int*)d_in[1];
    const int*   batch = (const int*)d_in[2];
    const float* W1 = (const float*)d_in[3];
    const float* b1 = (const float*)d_in[4];
    const float* g1 = (const float*)d_in[5];
    const float* t1 = (const float*)d_in[6];
    const float* m1 = (const float*)d_in[7];
    const float* v1 = (const float*)d_in[8];
    const float* W2 = (const float*)d_in[9];
    const float* b2 = (const float*)d_in[10];
    const float* g2 = (const float*)d_in[11];
    const float* t2 = (const float*)d_in[12];
    const float* m2 = (const float*)d_in[13];
    const float* v2 = (const float*)d_in[14];
    const float* W3 = (const float*)d_in[15];
    const float* b3 = (const float*)d_in[16];
    const float* g3 = (const float*)d_in[17];
    const float* t3 = (const float*)d_in[18];
    const float* m3 = (const float*)d_in[19];
    const float* v3 = (const float*)d_in[20];
    const float* fc1w = (const float*)d_in[21];
    const float* fc1b = (const float*)d_in[22];
    const float* fc2w = (const float*)d_in[23];
    const float* fc2b = (const float*)d_in[24];

    const int* src = ei;
    const int* dst = ei + N_EDGES;

    // ---- workspace ----
    char* ws = (char*)d_ws;
    size_t off = 0;
    auto alloc = [&](size_t bytes) -> char* {
        char* p = ws + off;
        off = (off + bytes + 511) & ~(size_t)511;
        return p;
    };
    // deg & cursor adjacent -> one memset clears both
    int*   deg     = (int*)  alloc((size_t)2 * N_NODES * 4);
    int*   cursor  = deg + N_NODES;
    float* dis     = (float*)alloc((size_t)N_NODES * 4);
    int*   rp      = (int*)  alloc(((size_t)N_NODES + 1) * 4);
    int*   blk     = (int*)  alloc((size_t)N_SCAN_BLK * 4);
    int*   col     = (int*)  alloc((size_t)N_EDGES * 4);
    int*   gp      = (int*)  alloc((size_t)(NG + 1) * 4);
    float* bnsc    = (float*)alloc((size_t)3 * DH * 4);
    float* bnsh    = (float*)alloc((size_t)3 * DH * 4);
    u16*   xb      = (u16*)  alloc((size_t)N_NODES * DIN * 2);
    u16*   Wt1     = (u16*)  alloc((size_t)DH * DIN * 2);
    u16*   Wt2     = (u16*)  alloc((size_t)DH * DH * 2);
    u16*   Wt3     = (u16*)  alloc((size_t)DH * DH * 2);
    u16*   bufB    = (u16*)  alloc((size_t)N_NODES * DH * 2);
    u16*   bufA    = (u16*)  alloc((size_t)N_NODES * DH * 2);

    const int TPB = 256;
    const int gGemm = (N_NODES + 63) / 64;                               // 1563
    const int gAgg  = (int)(((long)N_NODES * 32 + TPB - 1) / TPB);       // 12500

    // ---- prep: degrees + dtype conversions (one dispatch), scans, CSR ----
    hipMemsetAsync(deg, 0, (size_t)2 * N_NODES * 4, stream);
    degprep_kernel<<<PREP_TOTAL, TPB, 0, stream>>>(dst, deg, x, xb, W1, Wt1, W2, Wt2,
                                                   W3, Wt3,
                                                   b1, g1, t1, m1, v1,
                                                   b2, g2, t2, m2, v2,
                                                   b3, g3, t3, m3, v3,
                                                   bnsc, bnsh, batch, gp);
    scan1_kernel<<<N_SCAN_BLK, SCAN_TPB, 0, stream>>>(deg, dis, rp, blk, N_NODES);
    scan2_kernel<<<1, 512, 0, stream>>>(blk, N_SCAN_BLK);
    build_csr_kernel<<<G_EDGE, TPB, 0, stream>>>(src, dst, rp, blk, cursor, col, N_EDGES);

    // ---- layer 1 ----
    gemm_mfma<DIN><<<gGemm, TPB, 0, stream>>>(xb, Wt1, dis, bufB, N_NODES);
    agg_epi_kernel<false><<<gAgg, TPB, 0, stream>>>(bufB, rp, blk, col, dis,
                                                    bnsc, bnsh, bufA, N_NODES);
    // ---- layer 2 (residual, in-place on bufA) ----
    gemm_mfma<DH><<<gGemm, TPB, 0, stream>>>(bufA, Wt2, dis, bufB, N_NODES);
    agg_epi_kernel<true><<<gAgg, TPB, 0, stream>>>(bufB, rp, blk, col, dis,
                                                   bnsc + DH, bnsh + DH, bufA, N_NODES);
    // ---- layer 3 ----
    gemm_mfma<DH><<<gGemm, TPB, 0, stream>>>(bufA, Wt3, dis, bufB, N_NODES);
    agg_epi_kernel<false><<<gAgg, TPB, 0, stream>>>(bufB, rp, blk, col, dis,
                                                    bnsc + 2 * DH, bnsh + 2 * DH, bufA,
                                                    N_NODES);

    // ---- pool + head (fused) ----
    pool_head_kernel<<<NG, TPB, 0, stream>>>(bufA, gp, fc1w, fc1b, fc2w, fc2b,
                                             (float*)d_out);
}

// Round 9
// 289.928 us; speedup vs baseline: 1.2060x; 1.0175x over previous
//
#include <hip/hip_runtime.h>
#include <math.h>

#define N_NODES 100000
#define N_EDGES 600000
#define DIN     64
#define DH      128
#define NG      512
#define EPS_BN  1e-5f
#define SCAN_TPB 256
#define N_SCAN_BLK ((N_NODES + SCAN_TPB - 1) / SCAN_TPB)   // 391
#define G_EDGE   ((N_EDGES + 255) / 256)                   // 2344

typedef unsigned short u16;
typedef short s16x8 __attribute__((ext_vector_type(8)));
typedef float f32x4 __attribute__((ext_vector_type(4)));

__device__ __forceinline__ u16 f2bf(float x) {
    unsigned u = __builtin_bit_cast(unsigned, x);
    u += 0x7fffu + ((u >> 16) & 1u);   // round-to-nearest-even
    return (u16)(u >> 16);
}
__device__ __forceinline__ float bf2f(u16 h) {
    unsigned u = ((unsigned)h) << 16;
    return __builtin_bit_cast(float, u);
}

// ------- merged: degree histogram | Wt1..3 | bn fold | graph bounds -------
#define PREP_WT1_BLKS  32
#define PREP_WT2_BLKS  64
#define PREP_WT3_BLKS  64
#define PREP_BN_BLKS   2
#define PREP_GB_BLKS   3
#define PREP_B0 G_EDGE
#define PREP_B1 (PREP_B0 + PREP_WT1_BLKS)
#define PREP_B2 (PREP_B1 + PREP_WT2_BLKS)
#define PREP_B3 (PREP_B2 + PREP_WT3_BLKS)
#define PREP_B4 (PREP_B3 + PREP_BN_BLKS)
#define PREP_TOTAL (PREP_B4 + PREP_GB_BLKS)

__device__ __forceinline__ void wt_body(const float* __restrict__ W, u16* __restrict__ Wt,
                                        int K, int idx) {
    if (idx >= K * DH) return;
    int k = idx / DH, n = idx % DH;
    Wt[(long)n * K + k] = f2bf(W[idx]);
}

__global__ __launch_bounds__(256) void degprep_kernel(
    const int* __restrict__ dst, int* __restrict__ deg,
    const float* __restrict__ W1, u16* __restrict__ Wt1,
    const float* __restrict__ W2, u16* __restrict__ Wt2,
    const float* __restrict__ W3, u16* __restrict__ Wt3,
    const float* b1, const float* g1, const float* bb1, const float* m1, const float* v1,
    const float* b2, const float* g2, const float* bb2, const float* m2, const float* v2,
    const float* b3, const float* g3, const float* bb3, const float* m3, const float* v3,
    float* __restrict__ sc, float* __restrict__ sh,
    const int* __restrict__ batch, int* __restrict__ gp) {
    const int b = blockIdx.x;
    const int tid = threadIdx.x;
    if (b < PREP_B0) {
        const int e = b * 256 + tid;
        if (e < N_EDGES) atomicAdd(&deg[dst[e]], 1);
    } else if (b < PREP_B1) {
        wt_body(W1, Wt1, DIN, (b - PREP_B0) * 256 + tid);
    } else if (b < PREP_B2) {
        wt_body(W2, Wt2, DH, (b - PREP_B1) * 256 + tid);
    } else if (b < PREP_B3) {
        wt_body(W3, Wt3, DH, (b - PREP_B2) * 256 + tid);
    } else if (b < PREP_B4) {
        const int i = (b - PREP_B3) * 256 + tid;
        if (i < 3 * DH) {
            int l = i >> 7, c = i & (DH - 1);
            const float* bc = l == 0 ? b1 : (l == 1 ? b2 : b3);
            const float* g  = l == 0 ? g1 : (l == 1 ? g2 : g3);
            const float* bb = l == 0 ? bb1 : (l == 1 ? bb2 : bb3);
            const float* m  = l == 0 ? m1 : (l == 1 ? m2 : m3);
            const float* v  = l == 0 ? v1 : (l == 1 ? v2 : v3);
            float s = g[c] * rsqrtf(v[c] + EPS_BN);
            sc[i] = s;
            sh[i] = (bc[c] - m[c]) * s + bb[c];
        }
    } else {
        const int g = (b - PREP_B4) * 256 + tid;
        if (g <= NG) {
            int lo = 0, hi = N_NODES;
            while (lo < hi) {
                int mid = (lo + hi) >> 1;
                if (batch[mid] < g) lo = mid + 1; else hi = mid;
            }
            gp[g] = lo;
        }
    }
}

// ---------------- scan phase 1 (+ dis): local exclusive prefix + block sums ----------------
__global__ __launch_bounds__(SCAN_TPB) void scan1_kernel(const int* __restrict__ deg,
                                                         float* __restrict__ dis,
                                                         int* __restrict__ rp,
                                                         int* __restrict__ blk, int n) {
    __shared__ int sm[SCAN_TPB];
    const int t = threadIdx.x;
    const int i = blockIdx.x * SCAN_TPB + t;
    int v = 0;
    if (i < n) {
        v = deg[i];
        dis[i] = rsqrtf((float)v + 1.0f);   // +1 self loop
    }
    sm[t] = v;
    __syncthreads();
#pragma unroll
    for (int off = 1; off < SCAN_TPB; off <<= 1) {
        int u = (t >= off) ? sm[t - off] : 0;
        __syncthreads();
        sm[t] += u;
        __syncthreads();
    }
    if (i <= n) rp[i] = sm[t] - v;            // local exclusive prefix
    if (t == SCAN_TPB - 1) blk[blockIdx.x] = sm[t];
}

// ---------------- scan phase 2: exclusive scan of block sums (1 block) ----------------
__global__ __launch_bounds__(512) void scan2_kernel(int* __restrict__ blk, int nblk) {
    __shared__ int sm[512];
    const int t = threadIdx.x;
    const int v = (t < nblk) ? blk[t] : 0;
    sm[t] = v;
    __syncthreads();
#pragma unroll
    for (int off = 1; off < 512; off <<= 1) {
        int u = (t >= off) ? sm[t - off] : 0;
        __syncthreads();
        sm[t] += u;
        __syncthreads();
    }
    if (t < nblk) blk[t] = sm[t] - v;         // exclusive prefix of block sums
}

// -------- scatter edges into CSR (col only; row_ptr = rp[d] + blk[d>>8] on the fly) --------
__global__ __launch_bounds__(256) void build_csr_kernel(const int* __restrict__ src,
                                                        const int* __restrict__ dst,
                                                        const int* __restrict__ rp,
                                                        const int* __restrict__ blk,
                                                        int* __restrict__ cursor,
                                                        int* __restrict__ col, int E) {
    int e = blockIdx.x * blockDim.x + threadIdx.x;
    if (e >= E) return;
    const int s = src[e];
    const int d = dst[e];
    const int p = atomicAdd(&cursor[d], 1);
    col[rp[d] + blk[d >> 8] + p] = s;
}

// ---- MFMA GEMM: C[M,128] = (A[M,K] @ Wt^T) * dis[row]; A fp32 or bf16; LDS-staged stores ----
template <int K, bool AF32>
__global__ __launch_bounds__(256) void gemm_mfma(const void* __restrict__ Ain,
                                                 const u16* __restrict__ Wt,  // [128][K]
                                                 const float* __restrict__ dis,
                                                 u16* __restrict__ C,         // [M][128]
                                                 int M) {
    __shared__ u16 ldsc[4][16][DH];   // per-wave 16x128 bf16 tile, XOR-swizzled 16B blocks
    const int wave = threadIdx.x >> 6;
    const int lane = threadIdx.x & 63;
    const int r16 = lane & 15;
    const int kc  = lane >> 4;
    const long row0 = (long)blockIdx.x * 64 + wave * 16;

    f32x4 acc[8];
#pragma unroll
    for (int t = 0; t < 8; ++t)
#pragma unroll
        for (int q = 0; q < 4; ++q) acc[t][q] = 0.0f;

    long arow = row0 + r16;
    if (arow >= M) arow = M - 1;

#pragma unroll
    for (int ks = 0; ks < K; ks += 32) {
        s16x8 a;
        if constexpr (AF32) {
            const float* ap = (const float*)Ain + arow * K + ks + kc * 8;
            const float4 f0 = *(const float4*)(ap);
            const float4 f1 = *(const float4*)(ap + 4);
            a[0] = (short)f2bf(f0.x); a[1] = (short)f2bf(f0.y);
            a[2] = (short)f2bf(f0.z); a[3] = (short)f2bf(f0.w);
            a[4] = (short)f2bf(f1.x); a[5] = (short)f2bf(f1.y);
            a[6] = (short)f2bf(f1.z); a[7] = (short)f2bf(f1.w);
        } else {
            a = *(const s16x8*)((const u16*)Ain + arow * K + ks + kc * 8);
        }
#pragma unroll
        for (int t = 0; t < 8; ++t) {
            const s16x8 b = *(const s16x8*)(Wt + (long)(t * 16 + r16) * K + ks + kc * 8);
            acc[t] = __builtin_amdgcn_mfma_f32_16x16x32_bf16(a, b, acc[t], 0, 0, 0);
        }
    }

    // dis scale per output row held by this thread
    float dd[4];
#pragma unroll
    for (int q = 0; q < 4; ++q) {
        long r = row0 + kc * 4 + q;
        dd[q] = dis[r < M ? r : (M - 1)];
    }

    // stage to LDS: element (row, col) -> block (col>>3) XOR (row&7), offset col&7
#pragma unroll
    for (int t = 0; t < 8; ++t) {
        const int blkc = (t << 1) | (r16 >> 3);    // col>>3
        const int co = r16 & 7;
#pragma unroll
        for (int q = 0; q < 4; ++q) {
            const int row = kc * 4 + q;
            ldsc[wave][row][(((blkc ^ (row & 7)) << 3) | co)] = f2bf(acc[t][q] * dd[q]);
        }
    }
    // same-wave producer/consumer: compiler inserts lgkmcnt wait; no barrier needed.
#pragma unroll
    for (int it = 0; it < 4; ++it) {
        const int rl = (lane >> 4) + it * 4;       // local row 0..15
        const long row = row0 + rl;
        if (row < M) {
            const int phys = (lane & 15) ^ (rl & 7);
            const s16x8 v = *(const s16x8*)&ldsc[wave][rl][phys << 3];
            *(s16x8*)(C + row * DH + ((lane & 15) << 3)) = v;
        }
    }
}

// ---- fused: agg[d] = dis[d]*(Σ H[col] + H[d]); BN + ReLU [+res]; 2-way edge-parallel ----
template <bool RES>
__global__ __launch_bounds__(256) void agg_epi_kernel(const u16* __restrict__ H,
                                                      const int* __restrict__ rp,
                                                      const int* __restrict__ blk,
                                                      const int* __restrict__ col,
                                                      const float* __restrict__ dis,
                                                      const float* __restrict__ scl,
                                                      const float* __restrict__ shf,
                                                      u16* __restrict__ out, int n) {
    const long t = (long)blockIdx.x * blockDim.x + threadIdx.x;
    const int lane = (int)(t & 31);
    const long i = t >> 5;
    if (i >= n) return;
    const int cl = lane & 15;
    const int eh = lane >> 4;
    const int c = cl * 8;

    float acc[8] = {0, 0, 0, 0, 0, 0, 0, 0};
    if (eh == 0) {   // self row (already pre-scaled by dis[i] in gemm)
        const s16x8 hv = *(const s16x8*)(H + i * DH + c);
#pragma unroll
        for (int q = 0; q < 8; ++q) acc[q] = bf2f((u16)hv[q]);
    }

    const int beg = rp[i] + blk[i >> 8];
    const int end = rp[i + 1] + blk[(int)(i + 1) >> 8];
    for (int e = beg + eh; e < end; e += 2) {
        const int s = col[e];
        const s16x8 v = *(const s16x8*)(H + (long)s * DH + c);
#pragma unroll
        for (int q = 0; q < 8; ++q) acc[q] += bf2f((u16)v[q]);
    }

#pragma unroll
    for (int q = 0; q < 8; ++q) acc[q] += __shfl_xor(acc[q], 16);

    if (eh == 0) {
        const float dd = dis[i];
        const float4 s0 = *(const float4*)(scl + c);
        const float4 s1 = *(const float4*)(scl + c + 4);
        const float4 f0 = *(const float4*)(shf + c);
        const float4 f1 = *(const float4*)(shf + c + 4);
        const float sv[8] = {s0.x, s0.y, s0.z, s0.w, s1.x, s1.y, s1.z, s1.w};
        const float fv[8] = {f0.x, f0.y, f0.z, f0.w, f1.x, f1.y, f1.z, f1.w};

        float r[8];
#pragma unroll
        for (int q = 0; q < 8; ++q) r[q] = fmaxf(fmaf(acc[q] * dd, sv[q], fv[q]), 0.0f);
        if (RES) {
            const s16x8 rv = *(const s16x8*)(out + i * DH + c);
#pragma unroll
            for (int q = 0; q < 8; ++q) r[q] += bf2f((u16)rv[q]);
        }
        s16x8 ov;
#pragma unroll
        for (int q = 0; q < 8; ++q) ov[q] = (short)f2bf(r[q]);
        __builtin_nontemporal_store(ov, (s16x8*)(out + i * DH + c));
    }
}

// ------- fused mean-pool + MLP head: 1 block/graph -------
__global__ __launch_bounds__(256) void pool_head_kernel(const u16* __restrict__ h,
                                                        const int* __restrict__ gp,
                                                        const float* __restrict__ fc1w,
                                                        const float* __restrict__ fc1b,
                                                        const float* __restrict__ fc2w,
                                                        const float* __restrict__ fc2b,
                                                        float* __restrict__ out) {
    const int g = blockIdx.x;
    const int t = threadIdx.x;
    const int grp = t >> 4;
    const int cl = t & 15;
    const int c = cl * 8;
    const int beg = gp[g];
    const int end = gp[g + 1];

    float acc[8] = {0, 0, 0, 0, 0, 0, 0, 0};
    for (int i = beg + grp; i < end; i += 16) {
        const s16x8 v = *(const s16x8*)(h + (long)i * DH + c);
#pragma unroll
        for (int q = 0; q < 8; ++q) acc[q] += bf2f((u16)v[q]);
    }

    __shared__ float sm[16][DH];
    __shared__ float p[DH];
#pragma unroll
    for (int q = 0; q < 8; ++q) sm[grp][c + q] = acc[q];
    __syncthreads();

    if (t < DH) {
        float s = 0.0f;
#pragma unroll
        for (int r = 0; r < 16; ++r) s += sm[r][t];
        p[t] = s / fmaxf((float)(end - beg), 1.0f);
    }
    __syncthreads();

    if (t < 64) {
        float a = 0.0f;
#pragma unroll 4
        for (int k = 0; k < DH; ++k) a = fmaf(p[k], fc1w[(long)k * 64 + t], a);
        const float h1 = fmaxf(a + fc1b[t], 0.0f);
        float v = h1 * fc2w[t];
#pragma unroll
        for (int off = 32; off > 0; off >>= 1) v += __shfl_down(v, off);
        if (t == 0) out[g] = 1.0f / (1.0f + expf(-(v + fc2b[0])));
    }
}

// ---------------- launch ----------------
extern "C" void kernel_launch(void* const* d_in, const int* in_sizes, int n_in,
                              void* d_out, int out_size, void* d_ws, size_t ws_size,
                              hipStream_t stream) {
    const float* x     = (const float*)d_in[0];
    const int*   ei    = (const int*)d_in[1];
    const int*   batch = (const int*)d_in[2];
    const float* W1 = (const float*)d_in[3];
    const float* b1 = (const float*)d_in[4];
    const float* g1 = (const float*)d_in[5];
    const float* t1 = (const float*)d_in[6];
    const float* m1 = (const float*)d_in[7];
    const float* v1 = (const float*)d_in[8];
    const float* W2 = (const float*)d_in[9];
    const float* b2 = (const float*)d_in[10];
    const float* g2 = (const float*)d_in[11];
    const float* t2 = (const float*)d_in[12];
    const float* m2 = (const float*)d_in[13];
    const float* v2 = (const float*)d_in[14];
    const float* W3 = (const float*)d_in[15];
    const float* b3 = (const float*)d_in[16];
    const float* g3 = (const float*)d_in[17];
    const float* t3 = (const float*)d_in[18];
    const float* m3 = (const float*)d_in[19];
    const float* v3 = (const float*)d_in[20];
    const float* fc1w = (const float*)d_in[21];
    const float* fc1b = (const float*)d_in[22];
    const float* fc2w = (const float*)d_in[23];
    const float* fc2b = (const float*)d_in[24];

    const int* src = ei;
    const int* dst = ei + N_EDGES;

    // ---- workspace ----
    char* ws = (char*)d_ws;
    size_t off = 0;
    auto alloc = [&](size_t bytes) -> char* {
        char* p = ws + off;
        off = (off + bytes + 511) & ~(size_t)511;
        return p;
    };
    // deg & cursor adjacent -> one memset clears both
    int*   deg     = (int*)  alloc((size_t)2 * N_NODES * 4);
    int*   cursor  = deg + N_NODES;
    float* dis     = (float*)alloc((size_t)N_NODES * 4);
    int*   rp      = (int*)  alloc(((size_t)N_NODES + 1) * 4);
    int*   blk     = (int*)  alloc((size_t)N_SCAN_BLK * 4);
    int*   col     = (int*)  alloc((size_t)N_EDGES * 4);
    int*   gp      = (int*)  alloc((size_t)(NG + 1) * 4);
    float* bnsc    = (float*)alloc((size_t)3 * DH * 4);
    float* bnsh    = (float*)alloc((size_t)3 * DH * 4);
    u16*   Wt1     = (u16*)  alloc((size_t)DH * DIN * 2);
    u16*   Wt2     = (u16*)  alloc((size_t)DH * DH * 2);
    u16*   Wt3     = (u16*)  alloc((size_t)DH * DH * 2);
    u16*   bufB    = (u16*)  alloc((size_t)N_NODES * DH * 2);
    u16*   bufA    = (u16*)  alloc((size_t)N_NODES * DH * 2);

    const int TPB = 256;
    const int gGemm = (N_NODES + 63) / 64;                               // 1563
    const int gAgg  = (int)(((long)N_NODES * 32 + TPB - 1) / TPB);       // 12500

    // ---- prep: degrees + weight transposes (one dispatch), scans, CSR ----
    hipMemsetAsync(deg, 0, (size_t)2 * N_NODES * 4, stream);
    degprep_kernel<<<PREP_TOTAL, TPB, 0, stream>>>(dst, deg, W1, Wt1, W2, Wt2, W3, Wt3,
                                                   b1, g1, t1, m1, v1,
                                                   b2, g2, t2, m2, v2,
                                                   b3, g3, t3, m3, v3,
                                                   bnsc, bnsh, batch, gp);
    scan1_kernel<<<N_SCAN_BLK, SCAN_TPB, 0, stream>>>(deg, dis, rp, blk, N_NODES);
    scan2_kernel<<<1, 512, 0, stream>>>(blk, N_SCAN_BLK);
    build_csr_kernel<<<G_EDGE, TPB, 0, stream>>>(src, dst, rp, blk, cursor, col, N_EDGES);

    // ---- layer 1 (A = x, fp32 direct) ----
    gemm_mfma<DIN, true><<<gGemm, TPB, 0, stream>>>((const void*)x, Wt1, dis, bufB,
                                                    N_NODES);
    agg_epi_kernel<false><<<gAgg, TPB, 0, stream>>>(bufB, rp, blk, col, dis,
                                                    bnsc, bnsh, bufA, N_NODES);
    // ---- layer 2 (residual, in-place on bufA) ----
    gemm_mfma<DH, false><<<gGemm, TPB, 0, stream>>>((const void*)bufA, Wt2, dis, bufB,
                                                    N_NODES);
    agg_epi_kernel<true><<<gAgg, TPB, 0, stream>>>(bufB, rp, blk, col, dis,
                                                   bnsc + DH, bnsh + DH, bufA, N_NODES);
    // ---- layer 3 ----
    gemm_mfma<DH, false><<<gGemm, TPB, 0, stream>>>((const void*)bufA, Wt3, dis, bufB,
                                                    N_NODES);
    agg_epi_kernel<false><<<gAgg, TPB, 0, stream>>>(bufB, rp, blk, col, dis,
                                                    bnsc + 2 * DH, bnsh + 2 * DH, bufA,
                                                    N_NODES);

    // ---- pool + head (fused) ----
    pool_head_kernel<<<NG, TPB, 0, stream>>>(bufA, gp, fc1w, fc1b, fc2w, fc2b,
                                             (float*)d_out);
}

// Round 10
// 280.616 us; speedup vs baseline: 1.2460x; 1.0332x over previous
//
#include <hip/hip_runtime.h>
#include <math.h>

#define N_NODES 100000
#define N_EDGES 600000
#define DIN     64
#define DH      128
#define NG      512
#define EPS_BN  1e-5f
#define SCAN_TPB 256
#define N_SCAN_BLK ((N_NODES + SCAN_TPB - 1) / SCAN_TPB)   // 391
#define G_EDGE   ((N_EDGES + 255) / 256)                   // 2344

typedef unsigned short u16;
typedef short s16x8 __attribute__((ext_vector_type(8)));
typedef float f32x4 __attribute__((ext_vector_type(4)));

__device__ __forceinline__ u16 f2bf(float x) {
    unsigned u = __builtin_bit_cast(unsigned, x);
    u += 0x7fffu + ((u >> 16) & 1u);   // round-to-nearest-even
    return (u16)(u >> 16);
}
__device__ __forceinline__ float bf2f(u16 h) {
    unsigned u = ((unsigned)h) << 16;
    return __builtin_bit_cast(float, u);
}

// ------- merged: degree histogram | Wt1..3 | bn fold | graph bounds -------
#define PREP_WT1_BLKS  32
#define PREP_WT2_BLKS  64
#define PREP_WT3_BLKS  64
#define PREP_BN_BLKS   2
#define PREP_GB_BLKS   3
#define PREP_B0 G_EDGE
#define PREP_B1 (PREP_B0 + PREP_WT1_BLKS)
#define PREP_B2 (PREP_B1 + PREP_WT2_BLKS)
#define PREP_B3 (PREP_B2 + PREP_WT3_BLKS)
#define PREP_B4 (PREP_B3 + PREP_BN_BLKS)
#define PREP_TOTAL (PREP_B4 + PREP_GB_BLKS)

__device__ __forceinline__ void wt_body(const float* __restrict__ W, u16* __restrict__ Wt,
                                        int K, int idx) {
    if (idx >= K * DH) return;
    int k = idx / DH, n = idx % DH;
    Wt[(long)n * K + k] = f2bf(W[idx]);
}

__global__ __launch_bounds__(256) void degprep_kernel(
    const int* __restrict__ dst, int* __restrict__ deg,
    const float* __restrict__ W1, u16* __restrict__ Wt1,
    const float* __restrict__ W2, u16* __restrict__ Wt2,
    const float* __restrict__ W3, u16* __restrict__ Wt3,
    const float* b1, const float* g1, const float* bb1, const float* m1, const float* v1,
    const float* b2, const float* g2, const float* bb2, const float* m2, const float* v2,
    const float* b3, const float* g3, const float* bb3, const float* m3, const float* v3,
    float* __restrict__ sc, float* __restrict__ sh,
    const int* __restrict__ batch, int* __restrict__ gp) {
    const int b = blockIdx.x;
    const int tid = threadIdx.x;
    if (b < PREP_B0) {
        const int e = b * 256 + tid;
        if (e < N_EDGES) atomicAdd(&deg[dst[e]], 1);
    } else if (b < PREP_B1) {
        wt_body(W1, Wt1, DIN, (b - PREP_B0) * 256 + tid);
    } else if (b < PREP_B2) {
        wt_body(W2, Wt2, DH, (b - PREP_B1) * 256 + tid);
    } else if (b < PREP_B3) {
        wt_body(W3, Wt3, DH, (b - PREP_B2) * 256 + tid);
    } else if (b < PREP_B4) {
        const int i = (b - PREP_B3) * 256 + tid;
        if (i < 3 * DH) {
            int l = i >> 7, c = i & (DH - 1);
            const float* bc = l == 0 ? b1 : (l == 1 ? b2 : b3);
            const float* g  = l == 0 ? g1 : (l == 1 ? g2 : g3);
            const float* bb = l == 0 ? bb1 : (l == 1 ? bb2 : bb3);
            const float* m  = l == 0 ? m1 : (l == 1 ? m2 : m3);
            const float* v  = l == 0 ? v1 : (l == 1 ? v2 : v3);
            float s = g[c] * rsqrtf(v[c] + EPS_BN);
            sc[i] = s;
            sh[i] = (bc[c] - m[c]) * s + bb[c];
        }
    } else {
        const int g = (b - PREP_B4) * 256 + tid;
        if (g <= NG) {
            int lo = 0, hi = N_NODES;
            while (lo < hi) {
                int mid = (lo + hi) >> 1;
                if (batch[mid] < g) lo = mid + 1; else hi = mid;
            }
            gp[g] = lo;
        }
    }
}

// ---------------- scan phase 1 (+ dis): local exclusive prefix + block sums ----------------
__global__ __launch_bounds__(SCAN_TPB) void scan1_kernel(const int* __restrict__ deg,
                                                         float* __restrict__ dis,
                                                         int* __restrict__ rp,
                                                         int* __restrict__ blk, int n) {
    __shared__ int sm[SCAN_TPB];
    const int t = threadIdx.x;
    const int i = blockIdx.x * SCAN_TPB + t;
    int v = 0;
    if (i < n) {
        v = deg[i];
        dis[i] = rsqrtf((float)v + 1.0f);   // +1 self loop
    }
    sm[t] = v;
    __syncthreads();
#pragma unroll
    for (int off = 1; off < SCAN_TPB; off <<= 1) {
        int u = (t >= off) ? sm[t - off] : 0;
        __syncthreads();
        sm[t] += u;
        __syncthreads();
    }
    if (i <= n) rp[i] = sm[t] - v;            // local exclusive prefix
    if (t == SCAN_TPB - 1) blk[blockIdx.x] = sm[t];
}

// ---------------- scan phase 2: exclusive scan of block sums (1 block) ----------------
__global__ __launch_bounds__(512) void scan2_kernel(int* __restrict__ blk, int nblk) {
    __shared__ int sm[512];
    const int t = threadIdx.x;
    const int v = (t < nblk) ? blk[t] : 0;
    sm[t] = v;
    __syncthreads();
#pragma unroll
    for (int off = 1; off < 512; off <<= 1) {
        int u = (t >= off) ? sm[t - off] : 0;
        __syncthreads();
        sm[t] += u;
        __syncthreads();
    }
    if (t < nblk) blk[t] = sm[t] - v;         // exclusive prefix of block sums
}

// ---- merged: scatter edges into CSR (col only) | xcvt xb = bf16(x * dis[row]) ----
#define CSRX_XCVT_BLKS 3125          // 100000*64/8/256
#define CSRX_TOTAL (G_EDGE + CSRX_XCVT_BLKS)
__global__ __launch_bounds__(256) void csr_xcvt_kernel(const int* __restrict__ src,
                                                       const int* __restrict__ dst,
                                                       const int* __restrict__ rp,
                                                       const int* __restrict__ blk,
                                                       int* __restrict__ cursor,
                                                       int* __restrict__ col,
                                                       const float* __restrict__ x,
                                                       const float* __restrict__ dis,
                                                       u16* __restrict__ xb) {
    const int b = blockIdx.x;
    const int tid = threadIdx.x;
    if (b < G_EDGE) {
        const int e = b * 256 + tid;
        if (e >= N_EDGES) return;
        const int s = src[e];
        const int d = dst[e];
        const int p = atomicAdd(&cursor[d], 1);
        col[rp[d] + blk[d >> 8] + p] = s;
    } else {
        const long base = ((long)(b - G_EDGE) * 256 + tid) * 8;
        const float dd = dis[base >> 6];           // 8 elems stay within one 64-ch row
        const float4 a = *(const float4*)(x + base);
        const float4 c = *(const float4*)(x + base + 4);
        s16x8 o;
        o[0] = (short)f2bf(a.x * dd); o[1] = (short)f2bf(a.y * dd);
        o[2] = (short)f2bf(a.z * dd); o[3] = (short)f2bf(a.w * dd);
        o[4] = (short)f2bf(c.x * dd); o[5] = (short)f2bf(c.y * dd);
        o[6] = (short)f2bf(c.z * dd); o[7] = (short)f2bf(c.w * dd);
        *(s16x8*)(xb + base) = o;
    }
}

// ---- layer-1 aggregate in 64-dim input space: aggX[d] = dis[d]*(xb[d] + Σ xb[col]) ----
// 32 lanes/node: cl = lane&7 channel chunk (8 ch), eh = (lane>>3)&3 edge slot (4-way).
__global__ __launch_bounds__(256) void agg64_kernel(const u16* __restrict__ xb,
                                                    const int* __restrict__ rp,
                                                    const int* __restrict__ blk,
                                                    const int* __restrict__ col,
                                                    const float* __restrict__ dis,
                                                    u16* __restrict__ aggX, int n) {
    const long t = (long)blockIdx.x * blockDim.x + threadIdx.x;
    const int lane = (int)(t & 31);
    const long i = t >> 5;
    if (i >= n) return;
    const int cl = lane & 7;
    const int eh = (lane >> 3) & 3;
    const int c = cl * 8;

    float acc[8] = {0, 0, 0, 0, 0, 0, 0, 0};
    if (eh == 0) {   // self loop: xb already prescaled by dis[i]
        const s16x8 hv = *(const s16x8*)(xb + i * DIN + c);
#pragma unroll
        for (int q = 0; q < 8; ++q) acc[q] = bf2f((u16)hv[q]);
    }

    const int beg = rp[i] + blk[i >> 8];
    const int end = rp[i + 1] + blk[(int)(i + 1) >> 8];
    for (int e = beg + eh; e < end; e += 4) {
        const int s = col[e];
        const s16x8 v = *(const s16x8*)(xb + (long)s * DIN + c);
#pragma unroll
        for (int q = 0; q < 8; ++q) acc[q] += bf2f((u16)v[q]);
    }

#pragma unroll
    for (int q = 0; q < 8; ++q) acc[q] += __shfl_xor(acc[q], 8);
#pragma unroll
    for (int q = 0; q < 8; ++q) acc[q] += __shfl_xor(acc[q], 16);

    if (eh == 0 && (lane >> 4) == 0) {   // lanes 0..7 and 32..39
        const float dd = dis[i];
        s16x8 ov;
#pragma unroll
        for (int q = 0; q < 8; ++q) ov[q] = (short)f2bf(acc[q] * dd);
        *(s16x8*)(aggX + i * DIN + c) = ov;
    }
}

// ---- MFMA GEMM: C[M,128] = epi(A[M,K] @ Wt^T); epi = BN+ReLU (layer1) or dis-scale ----
template <int K, bool BN_EPI>
__global__ __launch_bounds__(256) void gemm_mfma(const u16* __restrict__ A,   // [M][K]
                                                 const u16* __restrict__ Wt,  // [128][K]
                                                 const float* __restrict__ dis,
                                                 const float* __restrict__ scl,
                                                 const float* __restrict__ shf,
                                                 u16* __restrict__ C,         // [M][128]
                                                 int M) {
    __shared__ u16 ldsc[4][16][DH];   // per-wave 16x128 bf16 tile, XOR-swizzled 16B blocks
    const int wave = threadIdx.x >> 6;
    const int lane = threadIdx.x & 63;
    const int r16 = lane & 15;
    const int kc  = lane >> 4;
    const long row0 = (long)blockIdx.x * 64 + wave * 16;

    f32x4 acc[8];
#pragma unroll
    for (int t = 0; t < 8; ++t)
#pragma unroll
        for (int q = 0; q < 4; ++q) acc[t][q] = 0.0f;

    long arow = row0 + r16;
    if (arow >= M) arow = M - 1;

#pragma unroll
    for (int ks = 0; ks < K; ks += 32) {
        const s16x8 a = *(const s16x8*)(A + arow * K + ks + kc * 8);
#pragma unroll
        for (int t = 0; t < 8; ++t) {
            const s16x8 b = *(const s16x8*)(Wt + (long)(t * 16 + r16) * K + ks + kc * 8);
            acc[t] = __builtin_amdgcn_mfma_f32_16x16x32_bf16(a, b, acc[t], 0, 0, 0);
        }
    }

    float dd[4], scv[8], shv[8];
    if constexpr (BN_EPI) {
#pragma unroll
        for (int t = 0; t < 8; ++t) {
            scv[t] = scl[t * 16 + r16];
            shv[t] = shf[t * 16 + r16];
        }
    } else {
#pragma unroll
        for (int q = 0; q < 4; ++q) {
            long r = row0 + kc * 4 + q;
            dd[q] = dis[r < M ? r : (M - 1)];
        }
    }

    // stage to LDS: element (row, col) -> block (col>>3) XOR (row&7), offset col&7
#pragma unroll
    for (int t = 0; t < 8; ++t) {
        const int blkc = (t << 1) | (r16 >> 3);    // col>>3
        const int co = r16 & 7;
#pragma unroll
        for (int q = 0; q < 4; ++q) {
            const int row = kc * 4 + q;
            float y;
            if constexpr (BN_EPI) {
                y = fmaxf(fmaf(acc[t][q], scv[t], shv[t]), 0.0f);
            } else {
                y = acc[t][q] * dd[q];
            }
            ldsc[wave][row][(((blkc ^ (row & 7)) << 3) | co)] = f2bf(y);
        }
    }
    // same-wave producer/consumer: compiler inserts lgkmcnt wait; no barrier needed.
#pragma unroll
    for (int it = 0; it < 4; ++it) {
        const int rl = (lane >> 4) + it * 4;       // local row 0..15
        const long row = row0 + rl;
        if (row < M) {
            const int phys = (lane & 15) ^ (rl & 7);
            const s16x8 v = *(const s16x8*)&ldsc[wave][rl][phys << 3];
            *(s16x8*)(C + row * DH + ((lane & 15) << 3)) = v;
        }
    }
}

// ---- fused: agg[d] = dis[d]*(Σ H[col] + H[d]); BN + ReLU [+res]; 2-way edge-parallel ----
template <bool RES>
__global__ __launch_bounds__(256) void agg_epi_kernel(const u16* __restrict__ H,
                                                      const int* __restrict__ rp,
                                                      const int* __restrict__ blk,
                                                      const int* __restrict__ col,
                                                      const float* __restrict__ dis,
                                                      const float* __restrict__ scl,
                                                      const float* __restrict__ shf,
                                                      u16* __restrict__ out, int n) {
    const long t = (long)blockIdx.x * blockDim.x + threadIdx.x;
    const int lane = (int)(t & 31);
    const long i = t >> 5;
    if (i >= n) return;
    const int cl = lane & 15;
    const int eh = lane >> 4;
    const int c = cl * 8;

    float acc[8] = {0, 0, 0, 0, 0, 0, 0, 0};
    if (eh == 0) {   // self row (already pre-scaled by dis[i] in gemm)
        const s16x8 hv = *(const s16x8*)(H + i * DH + c);
#pragma unroll
        for (int q = 0; q < 8; ++q) acc[q] = bf2f((u16)hv[q]);
    }

    const int beg = rp[i] + blk[i >> 8];
    const int end = rp[i + 1] + blk[(int)(i + 1) >> 8];
    for (int e = beg + eh; e < end; e += 2) {
        const int s = col[e];
        const s16x8 v = *(const s16x8*)(H + (long)s * DH + c);
#pragma unroll
        for (int q = 0; q < 8; ++q) acc[q] += bf2f((u16)v[q]);
    }

#pragma unroll
    for (int q = 0; q < 8; ++q) acc[q] += __shfl_xor(acc[q], 16);

    if (eh == 0) {
        const float dd = dis[i];
        const float4 s0 = *(const float4*)(scl + c);
        const float4 s1 = *(const float4*)(scl + c + 4);
        const float4 f0 = *(const float4*)(shf + c);
        const float4 f1 = *(const float4*)(shf + c + 4);
        const float sv[8] = {s0.x, s0.y, s0.z, s0.w, s1.x, s1.y, s1.z, s1.w};
        const float fv[8] = {f0.x, f0.y, f0.z, f0.w, f1.x, f1.y, f1.z, f1.w};

        float r[8];
#pragma unroll
        for (int q = 0; q < 8; ++q) r[q] = fmaxf(fmaf(acc[q] * dd, sv[q], fv[q]), 0.0f);
        if (RES) {
            const s16x8 rv = *(const s16x8*)(out + i * DH + c);
#pragma unroll
            for (int q = 0; q < 8; ++q) r[q] += bf2f((u16)rv[q]);
        }
        s16x8 ov;
#pragma unroll
        for (int q = 0; q < 8; ++q) ov[q] = (short)f2bf(r[q]);
        __builtin_nontemporal_store(ov, (s16x8*)(out + i * DH + c));
    }
}

// ------- fused mean-pool + MLP head: 1 block/graph -------
__global__ __launch_bounds__(256) void pool_head_kernel(const u16* __restrict__ h,
                                                        const int* __restrict__ gp,
                                                        const float* __restrict__ fc1w,
                                                        const float* __restrict__ fc1b,
                                                        const float* __restrict__ fc2w,
                                                        const float* __restrict__ fc2b,
                                                        float* __restrict__ out) {
    const int g = blockIdx.x;
    const int t = threadIdx.x;
    const int grp = t >> 4;
    const int cl = t & 15;
    const int c = cl * 8;
    const int beg = gp[g];
    const int end = gp[g + 1];

    float acc[8] = {0, 0, 0, 0, 0, 0, 0, 0};
    for (int i = beg + grp; i < end; i += 16) {
        const s16x8 v = *(const s16x8*)(h + (long)i * DH + c);
#pragma unroll
        for (int q = 0; q < 8; ++q) acc[q] += bf2f((u16)v[q]);
    }

    __shared__ float sm[16][DH];
    __shared__ float p[DH];
#pragma unroll
    for (int q = 0; q < 8; ++q) sm[grp][c + q] = acc[q];
    __syncthreads();

    if (t < DH) {
        float s = 0.0f;
#pragma unroll
        for (int r = 0; r < 16; ++r) s += sm[r][t];
        p[t] = s / fmaxf((float)(end - beg), 1.0f);
    }
    __syncthreads();

    if (t < 64) {
        float a = 0.0f;
#pragma unroll 4
        for (int k = 0; k < DH; ++k) a = fmaf(p[k], fc1w[(long)k * 64 + t], a);
        const float h1 = fmaxf(a + fc1b[t], 0.0f);
        float v = h1 * fc2w[t];
#pragma unroll
        for (int off = 32; off > 0; off >>= 1) v += __shfl_down(v, off);
        if (t == 0) out[g] = 1.0f / (1.0f + expf(-(v + fc2b[0])));
    }
}

// ---------------- launch ----------------
extern "C" void kernel_launch(void* const* d_in, const int* in_sizes, int n_in,
                              void* d_out, int out_size, void* d_ws, size_t ws_size,
                              hipStream_t stream) {
    const float* x     = (const float*)d_in[0];
    const int*   ei    = (const int*)d_in[1];
    const int*   batch = (const int*)d_in[2];
    const float* W1 = (const float*)d_in[3];
    const float* b1 = (const float*)d_in[4];
    const float* g1 = (const float*)d_in[5];
    const float* t1 = (const float*)d_in[6];
    const float* m1 = (const float*)d_in[7];
    const float* v1 = (const float*)d_in[8];
    const float* W2 = (const float*)d_in[9];
    const float* b2 = (const float*)d_in[10];
    const float* g2 = (const float*)d_in[11];
    const float* t2 = (const float*)d_in[12];
    const float* m2 = (const float*)d_in[13];
    const float* v2 = (const float*)d_in[14];
    const float* W3 = (const float*)d_in[15];
    const float* b3 = (const float*)d_in[16];
    const float* g3 = (const float*)d_in[17];
    const float* t3 = (const float*)d_in[18];
    const float* m3 = (const float*)d_in[19];
    const float* v3 = (const float*)d_in[20];
    const float* fc1w = (const float*)d_in[21];
    const float* fc1b = (const float*)d_in[22];
    const float* fc2w = (const float*)d_in[23];
    const float* fc2b = (const float*)d_in[24];

    const int* src = ei;
    const int* dst = ei + N_EDGES;

    // ---- workspace ----
    char* ws = (char*)d_ws;
    size_t off = 0;
    auto alloc = [&](size_t bytes) -> char* {
        char* p = ws + off;
        off = (off + bytes + 511) & ~(size_t)511;
        return p;
    };
    // deg & cursor adjacent -> one memset clears both
    int*   deg     = (int*)  alloc((size_t)2 * N_NODES * 4);
    int*   cursor  = deg + N_NODES;
    float* dis     = (float*)alloc((size_t)N_NODES * 4);
    int*   rp      = (int*)  alloc(((size_t)N_NODES + 1) * 4);
    int*   blk     = (int*)  alloc((size_t)N_SCAN_BLK * 4);
    int*   col     = (int*)  alloc((size_t)N_EDGES * 4);
    int*   gp      = (int*)  alloc((size_t)(NG + 1) * 4);
    float* bnsc    = (float*)alloc((size_t)3 * DH * 4);
    float* bnsh    = (float*)alloc((size_t)3 * DH * 4);
    u16*   Wt1     = (u16*)  alloc((size_t)DH * DIN * 2);
    u16*   Wt2     = (u16*)  alloc((size_t)DH * DH * 2);
    u16*   Wt3     = (u16*)  alloc((size_t)DH * DH * 2);
    u16*   xb      = (u16*)  alloc((size_t)N_NODES * DIN * 2);
    u16*   aggX    = (u16*)  alloc((size_t)N_NODES * DIN * 2);
    u16*   bufB    = (u16*)  alloc((size_t)N_NODES * DH * 2);
    u16*   bufA    = (u16*)  alloc((size_t)N_NODES * DH * 2);

    const int TPB = 256;
    const int gGemm = (N_NODES + 63) / 64;                               // 1563
    const int gAgg  = (int)(((long)N_NODES * 32 + TPB - 1) / TPB);       // 12500

    // ---- prep: degrees + weight transposes (one dispatch), scans, CSR+xcvt ----
    hipMemsetAsync(deg, 0, (size_t)2 * N_NODES * 4, stream);
    degprep_kernel<<<PREP_TOTAL, TPB, 0, stream>>>(dst, deg, W1, Wt1, W2, Wt2, W3, Wt3,
                                                   b1, g1, t1, m1, v1,
                                                   b2, g2, t2, m2, v2,
                                                   b3, g3, t3, m3, v3,
                                                   bnsc, bnsh, batch, gp);
    scan1_kernel<<<N_SCAN_BLK, SCAN_TPB, 0, stream>>>(deg, dis, rp, blk, N_NODES);
    scan2_kernel<<<1, 512, 0, stream>>>(blk, N_SCAN_BLK);
    csr_xcvt_kernel<<<CSRX_TOTAL, TPB, 0, stream>>>(src, dst, rp, blk, cursor, col,
                                                    x, dis, xb);

    // ---- layer 1: aggregate in 64-dim, then GEMM with BN+ReLU epilogue ----
    agg64_kernel<<<gAgg, TPB, 0, stream>>>(xb, rp, blk, col, dis, aggX, N_NODES);
    gemm_mfma<DIN, true><<<gGemm, TPB, 0, stream>>>(aggX, Wt1, dis, bnsc, bnsh, bufA,
                                                    N_NODES);
    // ---- layer 2 (residual, in-place on bufA) ----
    gemm_mfma<DH, false><<<gGemm, TPB, 0, stream>>>(bufA, Wt2, dis, bnsc, bnsh, bufB,
                                                    N_NODES);
    agg_epi_kernel<true><<<gAgg, TPB, 0, stream>>>(bufB, rp, blk, col, dis,
                                                   bnsc + DH, bnsh + DH, bufA, N_NODES);
    // ---- layer 3 ----
    gemm_mfma<DH, false><<<gGemm, TPB, 0, stream>>>(bufA, Wt3, dis, bnsc, bnsh, bufB,
                                                    N_NODES);
    agg_epi_kernel<false><<<gAgg, TPB, 0, stream>>>(bufB, rp, blk, col, dis,
                                                    bnsc + 2 * DH, bnsh + 2 * DH, bufA,
                                                    N_NODES);

    // ---- pool + head (fused) ----
    pool_head_kernel<<<NG, TPB, 0, stream>>>(bufA, gp, fc1w, fc1b, fc2w, fc2b,
                                             (float*)d_out);
}